// Round 1
// baseline (1023.269 us; speedup 1.0000x reference)
//
#include <hip/hip_runtime.h>
#include <stdint.h>

// ---- problem constants ----
#define TOK 144        // tokens per window
#define CD  384        // channels
#define NH  12         // heads
#define HDIM 32        // head dim
#define NWIN 1152      // total windows (B*nW)
#define MASKW 144      // mask windows (window index mod 144)
#define NQKV 1152      // 3*C

typedef __bf16 bf16_t;
typedef __bf16 bf16x4 __attribute__((ext_vector_type(4)));
typedef __bf16 bf16x8 __attribute__((ext_vector_type(8)));
typedef float  f32x4  __attribute__((ext_vector_type(4)));

// ------------------------------------------------------------------
// Kernel W: convert qkv_w (1152x384) and proj_w (384x384) to bf16.
// grid 576 x 256 threads, 4 elems/thread.
// ------------------------------------------------------------------
__global__ __launch_bounds__(256) void kconv(const float* __restrict__ qkvw,
                                             const float* __restrict__ projw,
                                             bf16_t* __restrict__ wq,
                                             bf16_t* __restrict__ wp)
{
    int i = (blockIdx.x * 256 + threadIdx.x) * 4;
    const int NQ = NQKV * CD;   // 442368
    if (i < NQ) {
        float4 v = *(const float4*)(qkvw + i);
        bf16x4 o = {(bf16_t)v.x, (bf16_t)v.y, (bf16_t)v.z, (bf16_t)v.w};
        *(bf16x4*)(wq + i) = o;
    } else {
        int j = i - NQ;
        if (j < CD * CD) {
            float4 v = *(const float4*)(projw + j);
            bf16x4 o = {(bf16_t)v.x, (bf16_t)v.y, (bf16_t)v.z, (bf16_t)v.w};
            *(bf16x4*)(wp + j) = o;
        }
    }
}

// ------------------------------------------------------------------
// Kernel 1: QKV GEMM.  A = x (fp32, staged->bf16), B = qkv_w bf16 [d][c].
// 128x128 tile, BK=32, 256 threads (4 waves, each 64x64 / 4x4 MFMA tiles).
// Output: Q (scaled, +bias), K (+bias), VT (+bias, transposed) per (win,head).
// ------------------------------------------------------------------
__global__ __launch_bounds__(256) void k_qkv(const float* __restrict__ x,
                                             const bf16_t* __restrict__ wB,
                                             const float* __restrict__ bias,
                                             bf16_t* __restrict__ Qp,
                                             bf16_t* __restrict__ Kp,
                                             bf16_t* __restrict__ VTp,
                                             int w0)
{
    // bijective XCD-chunked swizzle (m204): consecutive work per XCD
    int nwg = gridDim.x;
    int orig = blockIdx.x;
    int q8 = nwg >> 3, r8 = nwg & 7;
    int xcd = orig & 7, idx = orig >> 3;
    int wgid = (xcd < r8 ? xcd * (q8 + 1) : r8 * (q8 + 1) + (xcd - r8) * q8) + idx;
    int mb = wgid / 9, nb = wgid % 9;

    __shared__ bf16_t As[128][56];   // 16B-aligned row stride (112 B), 2-way banks
    __shared__ bf16_t Bs[128][56];

    int tid = threadIdx.x;
    int lane = tid & 63, wid = tid >> 6;
    int wr = (wid >> 1) * 64, wc = (wid & 1) * 64;
    int l15 = lane & 15, l4 = lane >> 4;

    f32x4 acc[4][4] = {};

    const size_t row0 = (size_t)w0 * 144 + (size_t)mb * 128;  // global x row

    for (int kk = 0; kk < 12; ++kk) {
        // stage A: 128x32 fp32 -> bf16
        {
            int r = tid >> 3, kq = tid & 7;
            #pragma unroll
            for (int p = 0; p < 4; ++p) {
                int row = r + p * 32;
                float4 v = *(const float4*)(x + (row0 + row) * 384 + kk * 32 + kq * 4);
                bf16x4 o = {(bf16_t)v.x, (bf16_t)v.y, (bf16_t)v.z, (bf16_t)v.w};
                *(bf16x4*)&As[row][kq * 4] = o;
            }
        }
        // stage B: 128x32 bf16 (16B chunks)
        {
            #pragma unroll
            for (int p = 0; p < 2; ++p) {
                int i2 = tid + p * 256;              // 0..511
                int row = i2 >> 2, c8 = (i2 & 3) * 8;
                uint4 v = *(const uint4*)(wB + (size_t)(nb * 128 + row) * 384 + kk * 32 + c8);
                *(uint4*)&Bs[row][c8] = v;
            }
        }
        __syncthreads();
        bf16x8 af[4], bfr[4];
        #pragma unroll
        for (int i = 0; i < 4; ++i) af[i]  = *(const bf16x8*)&As[wr + i * 16 + l15][l4 * 8];
        #pragma unroll
        for (int j = 0; j < 4; ++j) bfr[j] = *(const bf16x8*)&Bs[wc + j * 16 + l15][l4 * 8];
        #pragma unroll
        for (int i = 0; i < 4; ++i)
            #pragma unroll
            for (int j = 0; j < 4; ++j)
                acc[i][j] = __builtin_amdgcn_mfma_f32_16x16x32_bf16(af[i], bfr[j], acc[i][j], 0, 0, 0);
        __syncthreads();
    }

    // epilogue: +bias, scale q, scatter to Q/K/VT (bf16)
    const float SCALE = 0.17677669529663687f;   // 1/sqrt(32)
    #pragma unroll
    for (int j = 0; j < 4; ++j) {
        int d = nb * 128 + wc + j * 16 + l15;
        float bv = bias[d];
        int s = d / 384;
        int rr = d - s * 384;
        int h = rr >> 5, j32 = rr & 31;
        #pragma unroll
        for (int i = 0; i < 4; ++i) {
            #pragma unroll
            for (int r = 0; r < 4; ++r) {
                int lrow = mb * 128 + wr + i * 16 + l4 * 4 + r;  // chunk-local row
                int lw = lrow / 144;
                int n  = lrow - lw * 144;
                size_t off = (size_t)(lw * 12 + h) * 4608;
                float val = acc[i][j][r] + bv;
                if (s == 0)      Qp[off + n * 32 + j32]   = (bf16_t)(val * SCALE);
                else if (s == 1) Kp[off + n * 32 + j32]   = (bf16_t)val;
                else             VTp[off + j32 * 144 + n] = (bf16_t)val;
            }
        }
    }
}

// ------------------------------------------------------------------
// Kernel 2: attention per (window, head). 576 threads = 9 waves.
// Each wave owns 16 Q-rows: S = q k^T (9 MFMAs) + mask, in-register
// softmax (shfl within 16-lane groups), P->LDS, PV (10 MFMAs),
// normalize, store attn_out fp32 into d_out.
// dynamic LDS = 97,024 B.
// ------------------------------------------------------------------
__global__ __launch_bounds__(576) void k_attn(const bf16_t* __restrict__ Qp,
                                              const bf16_t* __restrict__ Kp,
                                              const bf16_t* __restrict__ VTp,
                                              const float* __restrict__ mask,
                                              float* __restrict__ out,
                                              int w0)
{
    extern __shared__ char smem[];
    bf16_t* qb  = (bf16_t*)smem;          // [144][56]
    bf16_t* kb  = qb + 144 * 56;          // [144][56]
    bf16_t* vtb = kb + 144 * 56;          // [32][184]
    bf16_t* pb  = vtb + 32 * 184;         // [144][184]

    int bw = blockIdx.x / 12, h = blockIdx.x % 12;
    int W = w0 + bw;
    size_t base = (size_t)(bw * 12 + h) * 4608;
    int tid = threadIdx.x;

    // stage q, k, vt (+ zero-pad vt cols 144..159)
    {
        int row = tid >> 2, c8 = (tid & 3) * 8;
        *(uint4*)&qb[row * 56 + c8] = *(const uint4*)(Qp + base + row * 32 + c8);
        *(uint4*)&kb[row * 56 + c8] = *(const uint4*)(Kp + base + row * 32 + c8);
        int j = tid / 18, seg = tid % 18;
        *(uint4*)&vtb[j * 184 + seg * 8] = *(const uint4*)(VTp + base + j * 144 + seg * 8);
        if (tid < 64) {
            int jj = tid >> 1, cc = 144 + (tid & 1) * 8;
            uint4 z = {0, 0, 0, 0};
            *(uint4*)&vtb[jj * 184 + cc] = z;
        }
    }
    __syncthreads();

    int lane = tid & 63, wv = tid >> 6;
    int l15 = lane & 15, l4 = lane >> 4;
    int row16 = wv * 16;
    const f32x4 fzero = {0.f, 0.f, 0.f, 0.f};

    // S = q k^T   (K=32, one MFMA per col-tile)
    bf16x8 aq = *(const bf16x8*)&qb[(row16 + l15) * 56 + l4 * 8];
    f32x4 s[9];
    #pragma unroll
    for (int nt = 0; nt < 9; ++nt) {
        bf16x8 bk = *(const bf16x8*)&kb[(nt * 16 + l15) * 56 + l4 * 8];
        s[nt] = __builtin_amdgcn_mfma_f32_16x16x32_bf16(aq, bk, fzero, 0, 0, 0);
    }
    // + mask[W % 144]
    const float* mrow = mask + (size_t)(W % MASKW) * (144 * 144);
    #pragma unroll
    for (int nt = 0; nt < 9; ++nt)
        #pragma unroll
        for (int r = 0; r < 4; ++r)
            s[nt][r] += mrow[(row16 + l4 * 4 + r) * 144 + nt * 16 + l15];

    // softmax over cols: reduce across tiles (local) x 16 lanes (shfl)
    float mx[4], sm[4];
    #pragma unroll
    for (int r = 0; r < 4; ++r) {
        float m = s[0][r];
        #pragma unroll
        for (int nt = 1; nt < 9; ++nt) m = fmaxf(m, s[nt][r]);
        #pragma unroll
        for (int off = 1; off < 16; off <<= 1) m = fmaxf(m, __shfl_xor(m, off, 64));
        mx[r] = m;
    }
    #pragma unroll
    for (int r = 0; r < 4; ++r) {
        float sum = 0.f;
        #pragma unroll
        for (int nt = 0; nt < 9; ++nt) {
            float e = __expf(s[nt][r] - mx[r]);
            s[nt][r] = e;
            sum += e;
        }
        #pragma unroll
        for (int off = 1; off < 16; off <<= 1) sum += __shfl_xor(sum, off, 64);
        sm[r] = sum;
    }

    // write P (unnormalized, bf16) to this wave's private pb rows; zero-pad k 144..159
    #pragma unroll
    for (int nt = 0; nt < 9; ++nt)
        #pragma unroll
        for (int r = 0; r < 4; ++r)
            pb[(row16 + l4 * 4 + r) * 184 + nt * 16 + l15] = (bf16_t)s[nt][r];
    {
        int rr = lane >> 2, cc = 144 + (lane & 3) * 4;
        uint2 z = {0, 0};
        *(uint2*)&pb[(row16 + rr) * 184 + cc] = z;
    }
    // PV: out16x32 = P(16x160) @ V(160x32)   (same-wave LDS, no barrier needed)
    f32x4 o0 = {0.f, 0.f, 0.f, 0.f}, o1 = {0.f, 0.f, 0.f, 0.f};
    #pragma unroll
    for (int ks = 0; ks < 5; ++ks) {
        bf16x8 ap  = *(const bf16x8*)&pb[(row16 + l15) * 184 + ks * 32 + l4 * 8];
        bf16x8 bv0 = *(const bf16x8*)&vtb[(l15) * 184 + ks * 32 + l4 * 8];
        bf16x8 bv1 = *(const bf16x8*)&vtb[(16 + l15) * 184 + ks * 32 + l4 * 8];
        o0 = __builtin_amdgcn_mfma_f32_16x16x32_bf16(ap, bv0, o0, 0, 0, 0);
        o1 = __builtin_amdgcn_mfma_f32_16x16x32_bf16(ap, bv1, o1, 0, 0, 0);
    }
    // normalize + store fp32 attn_out
    float inv[4];
    #pragma unroll
    for (int r = 0; r < 4; ++r) inv[r] = 1.0f / sm[r];
    size_t orow0 = (size_t)W * 144;
    #pragma unroll
    for (int r = 0; r < 4; ++r) {
        size_t o = (orow0 + row16 + l4 * 4 + r) * 384 + h * 32;
        out[o + l15]      = o0[r] * inv[r];
        out[o + 16 + l15] = o1[r] * inv[r];
    }
}

// ------------------------------------------------------------------
// Kernel 3: proj GEMM, in-place on d_out. Block = 128 rows x full N=384.
// 512 threads = 8 waves, each wave 16 rows x 384 cols (24 MFMA tiles).
// ------------------------------------------------------------------
__global__ __launch_bounds__(512) void k_proj(float* __restrict__ out,
                                              const bf16_t* __restrict__ wp,
                                              const float* __restrict__ bias)
{
    __shared__ bf16_t As[128][56];   // 14,336 B
    __shared__ bf16_t Bs[384][56];   // 43,008 B

    int tid = threadIdx.x;
    int lane = tid & 63, wid = tid >> 6;
    int l15 = lane & 15, l4 = lane >> 4;
    size_t row0 = (size_t)blockIdx.x * 128;

    f32x4 acc[24] = {};

    for (int kk = 0; kk < 12; ++kk) {
        // stage A: 128x32 fp32->bf16 (from d_out)
        #pragma unroll
        for (int p = 0; p < 2; ++p) {
            int i2 = tid + p * 512;            // 0..1023
            int row = i2 >> 3, kq = i2 & 7;
            float4 v = *(const float4*)(out + (row0 + row) * 384 + kk * 32 + kq * 4);
            bf16x4 o = {(bf16_t)v.x, (bf16_t)v.y, (bf16_t)v.z, (bf16_t)v.w};
            *(bf16x4*)&As[row][kq * 4] = o;
        }
        // stage B: 384x32 bf16
        #pragma unroll
        for (int p = 0; p < 3; ++p) {
            int i2 = tid + p * 512;            // 0..1535
            int row = i2 >> 2, c8 = (i2 & 3) * 8;
            uint4 v = *(const uint4*)(wp + (size_t)row * 384 + kk * 32 + c8);
            *(uint4*)&Bs[row][c8] = v;
        }
        __syncthreads();
        bf16x8 a = *(const bf16x8*)&As[wid * 16 + l15][l4 * 8];
        #pragma unroll
        for (int j = 0; j < 24; ++j) {
            bf16x8 b = *(const bf16x8*)&Bs[j * 16 + l15][l4 * 8];
            acc[j] = __builtin_amdgcn_mfma_f32_16x16x32_bf16(a, b, acc[j], 0, 0, 0);
        }
        __syncthreads();
    }
    #pragma unroll
    for (int j = 0; j < 24; ++j) {
        int col = j * 16 + l15;
        float bv = bias[col];
        #pragma unroll
        for (int r = 0; r < 4; ++r) {
            size_t row = row0 + wid * 16 + l4 * 4 + r;
            out[row * 384 + col] = acc[j][r] + bv;
        }
    }
}

// ------------------------------------------------------------------
extern "C" void kernel_launch(void* const* d_in, const int* in_sizes, int n_in,
                              void* d_out, int out_size, void* d_ws, size_t ws_size,
                              hipStream_t stream)
{
    const float* x     = (const float*)d_in[0];
    const float* mask  = (const float*)d_in[1];
    const float* qkvw  = (const float*)d_in[2];
    const float* qkvb  = (const float*)d_in[3];
    const float* projw = (const float*)d_in[4];
    const float* projb = (const float*)d_in[5];
    float* out = (float*)d_out;

    char* ws = (char*)d_ws;
    bf16_t* WQ = (bf16_t*)ws;                       // qkv_w bf16: 884,736 B
    bf16_t* WP = (bf16_t*)(ws + 884736);            // proj_w bf16: 294,912 B
    char* chunkbase = ws + 1179648;

    // pick window-chunk size from available workspace (deterministic per ws_size)
    size_t avail = ws_size > 1179648 ? ws_size - 1179648 : 0;
    long cw = (long)(avail / 331776);               // bytes per window (Q+K+VT bf16)
    cw = (cw / 8) * 8;
    if (cw > NWIN) cw = NWIN;
    if (cw < 8) cw = 8;

    size_t qbytes = (size_t)cw * 110592;
    bf16_t* Qp  = (bf16_t*)chunkbase;
    bf16_t* Kp  = (bf16_t*)(chunkbase + qbytes);
    bf16_t* VTp = (bf16_t*)(chunkbase + 2 * qbytes);

    kconv<<<576, 256, 0, stream>>>(qkvw, projw, WQ, WP);

    for (int w0 = 0; w0 < NWIN; w0 += (int)cw) {
        int c = (int)((NWIN - w0) < cw ? (NWIN - w0) : cw);
        int mblocks = (c * 144) / 128;
        k_qkv<<<mblocks * 9, 256, 0, stream>>>(x, WQ, qkvb, Qp, Kp, VTp, w0);
        k_attn<<<c * 12, 576, 97024, stream>>>(Qp, Kp, VTp, mask, out, w0);
    }
    k_proj<<<NWIN * 144 / 128, 512, 0, stream>>>(out, WP, projb);
}

// Round 2
// 973.140 us; speedup vs baseline: 1.0515x; 1.0515x over previous
//
#include <hip/hip_runtime.h>
#include <stdint.h>

// ---- problem constants ----
#define TOK 144        // tokens per window
#define CD  384        // channels
#define NH  12         // heads
#define HDIM 32        // head dim
#define NWIN 1152      // total windows (B*nW)
#define MASKW 144      // mask windows (window index mod 144)
#define NQKV 1152      // 3*C

typedef __bf16 bf16_t;
typedef __bf16 bf16x4 __attribute__((ext_vector_type(4)));
typedef __bf16 bf16x8 __attribute__((ext_vector_type(8)));
typedef float  f32x4  __attribute__((ext_vector_type(4)));

// async global->LDS, 16B per lane. LDS dest is wave-uniform base + lane*16.
__device__ __forceinline__ void gload16(const void* g, void* l) {
    __builtin_amdgcn_global_load_lds(
        (const __attribute__((address_space(1))) uint32_t*)g,
        (__attribute__((address_space(3))) uint32_t*)l, 16, 0, 0);
}

// ------------------------------------------------------------------
// Kernel W: convert qkv_w (1152x384) and proj_w (384x384) to bf16.
// ------------------------------------------------------------------
__global__ __launch_bounds__(256) void kconv(const float* __restrict__ qkvw,
                                             const float* __restrict__ projw,
                                             bf16_t* __restrict__ wq,
                                             bf16_t* __restrict__ wp)
{
    int i = (blockIdx.x * 256 + threadIdx.x) * 4;
    const int NQ = NQKV * CD;   // 442368
    if (i < NQ) {
        float4 v = *(const float4*)(qkvw + i);
        bf16x4 o = {(bf16_t)v.x, (bf16_t)v.y, (bf16_t)v.z, (bf16_t)v.w};
        *(bf16x4*)(wq + i) = o;
    } else {
        int j = i - NQ;
        if (j < CD * CD) {
            float4 v = *(const float4*)(projw + j);
            bf16x4 o = {(bf16_t)v.x, (bf16_t)v.y, (bf16_t)v.z, (bf16_t)v.w};
            *(bf16x4*)(wp + j) = o;
        }
    }
}

// ------------------------------------------------------------------
// Kernel X: convert a chunk of x (fp32) to bf16, 8 elems/thread.
// ------------------------------------------------------------------
__global__ __launch_bounds__(256) void kx(const float* __restrict__ x,
                                          bf16_t* __restrict__ xb, int n8)
{
    int i = blockIdx.x * 256 + threadIdx.x;
    if (i < n8) {
        float4 a = *(const float4*)(x + (size_t)i * 8);
        float4 b = *(const float4*)(x + (size_t)i * 8 + 4);
        bf16x8 o = {(bf16_t)a.x, (bf16_t)a.y, (bf16_t)a.z, (bf16_t)a.w,
                    (bf16_t)b.x, (bf16_t)b.y, (bf16_t)b.z, (bf16_t)b.w};
        *(bf16x8*)(xb + (size_t)i * 8) = o;
    }
}

// ------------------------------------------------------------------
// Kernel 1: QKV GEMM (m97 structure). A = xb bf16, B = qkv_w bf16 [d][c].
// 128x128 tile, BK=64, 256 threads (4 waves, each 64x64 / 4x4 MFMA tiles).
// A and B staged via global_load_lds (16B/lane), linear [128][64] LDS.
// Output: Q (scaled, +bias), K (+bias), VT (+bias, transposed) per (win,head).
// ------------------------------------------------------------------
__global__ __launch_bounds__(256) void k_qkv(const bf16_t* __restrict__ xb,
                                             const bf16_t* __restrict__ wB,
                                             const float* __restrict__ bias,
                                             bf16_t* __restrict__ Qp,
                                             bf16_t* __restrict__ Kp,
                                             bf16_t* __restrict__ VTp)
{
    // bijective XCD-chunked swizzle (m204)
    int nwg = gridDim.x;
    int orig = blockIdx.x;
    int q8 = nwg >> 3, r8 = nwg & 7;
    int xcd = orig & 7, idx = orig >> 3;
    int wgid = (xcd < r8 ? xcd * (q8 + 1) : r8 * (q8 + 1) + (xcd - r8) * q8) + idx;
    int mb = wgid / 9, nb = wgid % 9;

    __shared__ bf16_t As[128 * 64];   // 16 KB, linear (required by gload_lds)
    __shared__ bf16_t Bs[128 * 64];   // 16 KB

    int tid = threadIdx.x;
    int lane = tid & 63, wid = tid >> 6;
    int wr = (wid >> 1) * 64, wc = (wid & 1) * 64;
    int l15 = lane & 15, l4 = lane >> 4;
    int lr8 = lane >> 3, lc8 = lane & 7;     // row-in-8-row-chunk, 16B slot

    f32x4 acc[4][4] = {};

    // staging source bases: wave w stages chunks w*4+p (p=0..3), 8 rows each
    const size_t arow0 = (size_t)mb * 128;
    const bf16_t* aG = xb + (arow0 + (size_t)(wid * 4) * 8 + lr8) * 384 + lc8 * 8;
    const bf16_t* bG = wB + ((size_t)nb * 128 + (size_t)(wid * 4) * 8 + lr8) * 384 + lc8 * 8;

    for (int kk = 0; kk < 6; ++kk) {
        #pragma unroll
        for (int p = 0; p < 4; ++p)
            gload16(aG + (size_t)p * (8 * 384) + kk * 64, As + (wid * 4 + p) * 512);
        #pragma unroll
        for (int p = 0; p < 4; ++p)
            gload16(bG + (size_t)p * (8 * 384) + kk * 64, Bs + (wid * 4 + p) * 512);
        __syncthreads();   // compiler drains vmcnt(0) before barrier

        #pragma unroll
        for (int kh = 0; kh < 2; ++kh) {
            bf16x8 af[4], bfr[4];
            #pragma unroll
            for (int i = 0; i < 4; ++i)
                af[i] = *(const bf16x8*)&As[(wr + i * 16 + l15) * 64 + kh * 32 + l4 * 8];
            #pragma unroll
            for (int j = 0; j < 4; ++j)
                bfr[j] = *(const bf16x8*)&Bs[(wc + j * 16 + l15) * 64 + kh * 32 + l4 * 8];
            #pragma unroll
            for (int i = 0; i < 4; ++i)
                #pragma unroll
                for (int j = 0; j < 4; ++j)
                    acc[i][j] = __builtin_amdgcn_mfma_f32_16x16x32_bf16(af[i], bfr[j], acc[i][j], 0, 0, 0);
        }
        __syncthreads();
    }

    // epilogue: +bias, scale q, scatter to Q/K/VT (bf16)
    const float SCALE = 0.17677669529663687f;   // 1/sqrt(32)
    #pragma unroll
    for (int j = 0; j < 4; ++j) {
        int d = nb * 128 + wc + j * 16 + l15;
        float bv = bias[d];
        int s = d / 384;
        int rr = d - s * 384;
        int h = rr >> 5, j32 = rr & 31;
        #pragma unroll
        for (int i = 0; i < 4; ++i) {
            #pragma unroll
            for (int r = 0; r < 4; ++r) {
                int lrow = mb * 128 + wr + i * 16 + l4 * 4 + r;  // chunk-local row
                int lw = lrow / 144;
                int n  = lrow - lw * 144;
                size_t off = (size_t)(lw * 12 + h) * 4608;
                float val = acc[i][j][r] + bv;
                if (s == 0)      Qp[off + n * 32 + j32]   = (bf16_t)(val * SCALE);
                else if (s == 1) Kp[off + n * 32 + j32]   = (bf16_t)val;
                else             VTp[off + j32 * 144 + n] = (bf16_t)val;
            }
        }
    }
}

// ------------------------------------------------------------------
// Kernel 2: attention per (window, head). 576 threads = 9 waves.
// ------------------------------------------------------------------
__global__ __launch_bounds__(576) void k_attn(const bf16_t* __restrict__ Qp,
                                              const bf16_t* __restrict__ Kp,
                                              const bf16_t* __restrict__ VTp,
                                              const float* __restrict__ mask,
                                              float* __restrict__ out,
                                              int w0)
{
    extern __shared__ char smem[];
    bf16_t* qb  = (bf16_t*)smem;          // [144][56]
    bf16_t* kb  = qb + 144 * 56;          // [144][56]
    bf16_t* vtb = kb + 144 * 56;          // [32][184]
    bf16_t* pb  = vtb + 32 * 184;         // [144][184]

    int bw = blockIdx.x / 12, h = blockIdx.x % 12;
    int W = w0 + bw;
    size_t base = (size_t)(bw * 12 + h) * 4608;
    int tid = threadIdx.x;

    {
        int row = tid >> 2, c8 = (tid & 3) * 8;
        *(uint4*)&qb[row * 56 + c8] = *(const uint4*)(Qp + base + row * 32 + c8);
        *(uint4*)&kb[row * 56 + c8] = *(const uint4*)(Kp + base + row * 32 + c8);
        int j = tid / 18, seg = tid % 18;
        *(uint4*)&vtb[j * 184 + seg * 8] = *(const uint4*)(VTp + base + j * 144 + seg * 8);
        if (tid < 64) {
            int jj = tid >> 1, cc = 144 + (tid & 1) * 8;
            uint4 z = {0, 0, 0, 0};
            *(uint4*)&vtb[jj * 184 + cc] = z;
        }
    }
    __syncthreads();

    int lane = tid & 63, wv = tid >> 6;
    int l15 = lane & 15, l4 = lane >> 4;
    int row16 = wv * 16;
    const f32x4 fzero = {0.f, 0.f, 0.f, 0.f};

    bf16x8 aq = *(const bf16x8*)&qb[(row16 + l15) * 56 + l4 * 8];
    f32x4 s[9];
    #pragma unroll
    for (int nt = 0; nt < 9; ++nt) {
        bf16x8 bk = *(const bf16x8*)&kb[(nt * 16 + l15) * 56 + l4 * 8];
        s[nt] = __builtin_amdgcn_mfma_f32_16x16x32_bf16(aq, bk, fzero, 0, 0, 0);
    }
    const float* mrow = mask + (size_t)(W % MASKW) * (144 * 144);
    #pragma unroll
    for (int nt = 0; nt < 9; ++nt)
        #pragma unroll
        for (int r = 0; r < 4; ++r)
            s[nt][r] += mrow[(row16 + l4 * 4 + r) * 144 + nt * 16 + l15];

    float mx[4], sm[4];
    #pragma unroll
    for (int r = 0; r < 4; ++r) {
        float m = s[0][r];
        #pragma unroll
        for (int nt = 1; nt < 9; ++nt) m = fmaxf(m, s[nt][r]);
        #pragma unroll
        for (int off = 1; off < 16; off <<= 1) m = fmaxf(m, __shfl_xor(m, off, 64));
        mx[r] = m;
    }
    #pragma unroll
    for (int r = 0; r < 4; ++r) {
        float sum = 0.f;
        #pragma unroll
        for (int nt = 0; nt < 9; ++nt) {
            float e = __expf(s[nt][r] - mx[r]);
            s[nt][r] = e;
            sum += e;
        }
        #pragma unroll
        for (int off = 1; off < 16; off <<= 1) sum += __shfl_xor(sum, off, 64);
        sm[r] = sum;
    }

    #pragma unroll
    for (int nt = 0; nt < 9; ++nt)
        #pragma unroll
        for (int r = 0; r < 4; ++r)
            pb[(row16 + l4 * 4 + r) * 184 + nt * 16 + l15] = (bf16_t)s[nt][r];
    {
        int rr = lane >> 2, cc = 144 + (lane & 3) * 4;
        uint2 z = {0, 0};
        *(uint2*)&pb[(row16 + rr) * 184 + cc] = z;
    }
    f32x4 o0 = {0.f, 0.f, 0.f, 0.f}, o1 = {0.f, 0.f, 0.f, 0.f};
    #pragma unroll
    for (int ks = 0; ks < 5; ++ks) {
        bf16x8 ap  = *(const bf16x8*)&pb[(row16 + l15) * 184 + ks * 32 + l4 * 8];
        bf16x8 bv0 = *(const bf16x8*)&vtb[(l15) * 184 + ks * 32 + l4 * 8];
        bf16x8 bv1 = *(const bf16x8*)&vtb[(16 + l15) * 184 + ks * 32 + l4 * 8];
        o0 = __builtin_amdgcn_mfma_f32_16x16x32_bf16(ap, bv0, o0, 0, 0, 0);
        o1 = __builtin_amdgcn_mfma_f32_16x16x32_bf16(ap, bv1, o1, 0, 0, 0);
    }
    float inv[4];
    #pragma unroll
    for (int r = 0; r < 4; ++r) inv[r] = 1.0f / sm[r];
    size_t orow0 = (size_t)W * 144;
    #pragma unroll
    for (int r = 0; r < 4; ++r) {
        size_t o = (orow0 + row16 + l4 * 4 + r) * 384 + h * 32;
        out[o + l15]      = o0[r] * inv[r];
        out[o + 16 + l15] = o1[r] * inv[r];
    }
}

// ------------------------------------------------------------------
// Kernel 3: proj GEMM, in-place on d_out. Block = 128 rows x full N=384.
// ------------------------------------------------------------------
__global__ __launch_bounds__(512) void k_proj(float* __restrict__ out,
                                              const bf16_t* __restrict__ wp,
                                              const float* __restrict__ bias)
{
    __shared__ bf16_t As[128][56];   // 14,336 B
    __shared__ bf16_t Bs[384][56];   // 43,008 B

    int tid = threadIdx.x;
    int lane = tid & 63, wid = tid >> 6;
    int l15 = lane & 15, l4 = lane >> 4;
    size_t row0 = (size_t)blockIdx.x * 128;

    f32x4 acc[24] = {};

    for (int kk = 0; kk < 12; ++kk) {
        #pragma unroll
        for (int p = 0; p < 2; ++p) {
            int i2 = tid + p * 512;
            int row = i2 >> 3, kq = i2 & 7;
            float4 v = *(const float4*)(out + (row0 + row) * 384 + kk * 32 + kq * 4);
            bf16x4 o = {(bf16_t)v.x, (bf16_t)v.y, (bf16_t)v.z, (bf16_t)v.w};
            *(bf16x4*)&As[row][kq * 4] = o;
        }
        #pragma unroll
        for (int p = 0; p < 3; ++p) {
            int i2 = tid + p * 512;
            int row = i2 >> 2, c8 = (i2 & 3) * 8;
            uint4 v = *(const uint4*)(wp + (size_t)row * 384 + kk * 32 + c8);
            *(uint4*)&Bs[row][c8] = v;
        }
        __syncthreads();
        bf16x8 a = *(const bf16x8*)&As[wid * 16 + l15][l4 * 8];
        #pragma unroll
        for (int j = 0; j < 24; ++j) {
            bf16x8 b = *(const bf16x8*)&Bs[j * 16 + l15][l4 * 8];
            acc[j] = __builtin_amdgcn_mfma_f32_16x16x32_bf16(a, b, acc[j], 0, 0, 0);
        }
        __syncthreads();
    }
    #pragma unroll
    for (int j = 0; j < 24; ++j) {
        int col = j * 16 + l15;
        float bv = bias[col];
        #pragma unroll
        for (int r = 0; r < 4; ++r) {
            size_t row = row0 + wid * 16 + l4 * 4 + r;
            out[row * 384 + col] = acc[j][r] + bv;
        }
    }
}

// ------------------------------------------------------------------
extern "C" void kernel_launch(void* const* d_in, const int* in_sizes, int n_in,
                              void* d_out, int out_size, void* d_ws, size_t ws_size,
                              hipStream_t stream)
{
    const float* x     = (const float*)d_in[0];
    const float* mask  = (const float*)d_in[1];
    const float* qkvw  = (const float*)d_in[2];
    const float* qkvb  = (const float*)d_in[3];
    const float* projw = (const float*)d_in[4];
    const float* projb = (const float*)d_in[5];
    float* out = (float*)d_out;

    char* ws = (char*)d_ws;
    bf16_t* WQ = (bf16_t*)ws;                       // qkv_w bf16: 884,736 B
    bf16_t* WP = (bf16_t*)(ws + 884736);            // proj_w bf16: 294,912 B
    char* chunkbase = ws + 1179648;

    // per-window bytes: xb + Q + K + VT (all bf16) = 4 * 110,592
    size_t avail = ws_size > 1179648 ? ws_size - 1179648 : 0;
    long cw = (long)(avail / 442368);
    cw = (cw / 16) * 16;                            // 16 windows = 2304 rows = 9*256
    if (cw > NWIN) cw = NWIN;
    if (cw < 16) cw = 16;

    size_t qbytes = (size_t)cw * 110592;
    bf16_t* Xb  = (bf16_t*)chunkbase;
    bf16_t* Qp  = (bf16_t*)(chunkbase + qbytes);
    bf16_t* Kp  = (bf16_t*)(chunkbase + 2 * qbytes);
    bf16_t* VTp = (bf16_t*)(chunkbase + 3 * qbytes);

    kconv<<<576, 256, 0, stream>>>(qkvw, projw, WQ, WP);

    for (int w0 = 0; w0 < NWIN; w0 += (int)cw) {
        int c = (int)((NWIN - w0) < cw ? (NWIN - w0) : cw);
        int n8 = c * 6912;                        // bf16x8 groups in chunk
        kx<<<(n8 + 255) / 256, 256, 0, stream>>>(x + (size_t)w0 * 144 * 384, Xb, n8);
        int mblocks = (c * 144) / 128;
        k_qkv<<<mblocks * 9, 256, 0, stream>>>(Xb, WQ, qkvb, Qp, Kp, VTp);
        k_attn<<<c * 12, 576, 97024, stream>>>(Qp, Kp, VTp, mask, out, w0);
    }
    k_proj<<<NWIN * 144 / 128, 512, 0, stream>>>(out, WP, projb);
}

// Round 3
// 821.660 us; speedup vs baseline: 1.2454x; 1.1844x over previous
//
#include <hip/hip_runtime.h>
#include <stdint.h>

// ---- problem constants ----
#define TOK 144        // tokens per window
#define CD  384        // channels
#define NH  12         // heads
#define HDIM 32        // head dim
#define NWIN 1152      // total windows (B*nW)
#define MASKW 144      // mask windows (window index mod 144)
#define NQKV 1152      // 3*C

typedef __bf16 bf16_t;
typedef __bf16 bf16x4 __attribute__((ext_vector_type(4)));
typedef __bf16 bf16x8 __attribute__((ext_vector_type(8)));
typedef float  f32x4  __attribute__((ext_vector_type(4)));

// async global->LDS, 16B per lane. LDS dest is wave-uniform base + lane*16.
__device__ __forceinline__ void gload16(const void* g, void* l) {
    __builtin_amdgcn_global_load_lds(
        (const __attribute__((address_space(1))) uint32_t*)g,
        (__attribute__((address_space(3))) uint32_t*)l, 16, 0, 0);
}

// ------------------------------------------------------------------
// Kernel W: convert qkv_w (1152x384) and proj_w (384x384) to bf16.
// ------------------------------------------------------------------
__global__ __launch_bounds__(256) void kconv(const float* __restrict__ qkvw,
                                             const float* __restrict__ projw,
                                             bf16_t* __restrict__ wq,
                                             bf16_t* __restrict__ wp)
{
    int i = (blockIdx.x * 256 + threadIdx.x) * 4;
    const int NQ = NQKV * CD;   // 442368
    if (i < NQ) {
        float4 v = *(const float4*)(qkvw + i);
        bf16x4 o = {(bf16_t)v.x, (bf16_t)v.y, (bf16_t)v.z, (bf16_t)v.w};
        *(bf16x4*)(wq + i) = o;
    } else {
        int j = i - NQ;
        if (j < CD * CD) {
            float4 v = *(const float4*)(projw + j);
            bf16x4 o = {(bf16_t)v.x, (bf16_t)v.y, (bf16_t)v.z, (bf16_t)v.w};
            *(bf16x4*)(wp + j) = o;
        }
    }
}

// ------------------------------------------------------------------
// Kernel X: convert a chunk of x (fp32) to bf16, 8 elems/thread.
// ------------------------------------------------------------------
__global__ __launch_bounds__(256) void kx(const float* __restrict__ x,
                                          bf16_t* __restrict__ xb, int n8)
{
    int i = blockIdx.x * 256 + threadIdx.x;
    if (i < n8) {
        float4 a = *(const float4*)(x + (size_t)i * 8);
        float4 b = *(const float4*)(x + (size_t)i * 8 + 4);
        bf16x8 o = {(bf16_t)a.x, (bf16_t)a.y, (bf16_t)a.z, (bf16_t)a.w,
                    (bf16_t)b.x, (bf16_t)b.y, (bf16_t)b.z, (bf16_t)b.w};
        *(bf16x8*)(xb + (size_t)i * 8) = o;
    }
}

// ------------------------------------------------------------------
// Kernel 1: QKV GEMM (m97 structure). A = xb bf16, B = qkv_w bf16 [d][c].
// 128x128 tile, BK=64, 256 threads (4 waves, each 64x64 / 4x4 MFMA tiles).
// A and B staged via global_load_lds (16B/lane), linear [128][64] LDS.
// Epilogue through LDS: acc -> 128x136 bf16 tile -> vectorized 16B stores.
// Since 384 = 3*128, each nb block is uniformly Q (nb<3), K (3..5), V (6..8).
// ------------------------------------------------------------------
__global__ __launch_bounds__(256) void k_qkv(const bf16_t* __restrict__ xb,
                                             const bf16_t* __restrict__ wB,
                                             const float* __restrict__ bias,
                                             bf16_t* __restrict__ Qp,
                                             bf16_t* __restrict__ Kp,
                                             bf16_t* __restrict__ VTp)
{
    // bijective XCD-chunked swizzle (m204)
    int nwg = gridDim.x;
    int orig = blockIdx.x;
    int q8 = nwg >> 3, r8 = nwg & 7;
    int xcd = orig & 7, idx = orig >> 3;
    int wgid = (xcd < r8 ? xcd * (q8 + 1) : r8 * (q8 + 1) + (xcd - r8) * q8) + idx;
    int mb = wgid / 9, nb = wgid % 9;

    __shared__ union SMem {
        struct { bf16_t A[128 * 64]; bf16_t B[128 * 64]; } st;  // 32 KB staging
        bf16_t tile[128 * 136];                                  // 34,816 B epilogue
    } sm;
    bf16_t* As = sm.st.A;
    bf16_t* Bs = sm.st.B;

    int tid = threadIdx.x;
    int lane = tid & 63, wid = tid >> 6;
    int wr = (wid >> 1) * 64, wc = (wid & 1) * 64;
    int l15 = lane & 15, l4 = lane >> 4;
    int lr8 = lane >> 3, lc8 = lane & 7;     // row-in-8-row-chunk, 16B slot

    f32x4 acc[4][4] = {};

    const size_t arow0 = (size_t)mb * 128;
    const bf16_t* aG = xb + (arow0 + (size_t)(wid * 4) * 8 + lr8) * 384 + lc8 * 8;
    const bf16_t* bG = wB + ((size_t)nb * 128 + (size_t)(wid * 4) * 8 + lr8) * 384 + lc8 * 8;

    for (int kk = 0; kk < 6; ++kk) {
        #pragma unroll
        for (int p = 0; p < 4; ++p)
            gload16(aG + (size_t)p * (8 * 384) + kk * 64, As + (wid * 4 + p) * 512);
        #pragma unroll
        for (int p = 0; p < 4; ++p)
            gload16(bG + (size_t)p * (8 * 384) + kk * 64, Bs + (wid * 4 + p) * 512);
        __syncthreads();

        #pragma unroll
        for (int kh = 0; kh < 2; ++kh) {
            bf16x8 af[4], bfr[4];
            #pragma unroll
            for (int i = 0; i < 4; ++i)
                af[i] = *(const bf16x8*)&As[(wr + i * 16 + l15) * 64 + kh * 32 + l4 * 8];
            #pragma unroll
            for (int j = 0; j < 4; ++j)
                bfr[j] = *(const bf16x8*)&Bs[(wc + j * 16 + l15) * 64 + kh * 32 + l4 * 8];
            #pragma unroll
            for (int i = 0; i < 4; ++i)
                #pragma unroll
                for (int j = 0; j < 4; ++j)
                    acc[i][j] = __builtin_amdgcn_mfma_f32_16x16x32_bf16(af[i], bfr[j], acc[i][j], 0, 0, 0);
        }
        __syncthreads();
    }

    // ---- epilogue: acc (+bias, q-scale) -> LDS tile -> vectorized stores ----
    const int S = 136;                                   // row stride (272 B, 16B-aligned)
    const float SCALE = 0.17677669529663687f;            // 1/sqrt(32)
    float scl = (nb < 3) ? SCALE : 1.0f;
    float bv[4];
    #pragma unroll
    for (int j = 0; j < 4; ++j) bv[j] = bias[nb * 128 + wc + j * 16 + l15];

    #pragma unroll
    for (int i = 0; i < 4; ++i)
        #pragma unroll
        for (int j = 0; j < 4; ++j)
            #pragma unroll
            for (int r = 0; r < 4; ++r)
                sm.tile[(wr + i * 16 + l4 * 4 + r) * S + wc + j * 16 + l15] =
                    (bf16_t)((acc[i][j][r] + bv[j]) * scl);
    __syncthreads();

    if (nb < 6) {
        // Q/K: row-major readout, 16B stores
        bf16_t* dst = (nb < 3) ? Qp : Kp;
        int db0 = (nb % 3) * 128;
        #pragma unroll
        for (int it = 0; it < 8; ++it) {
            int item = tid + it * 256;            // 0..2047
            int row = item >> 4, ch = item & 15;
            bf16x8 v = *(const bf16x8*)&sm.tile[row * S + ch * 8];
            int gr = mb * 128 + row;
            int lw = gr / 144, n = gr - lw * 144;
            int dl = db0 + ch * 8;
            int h = dl >> 5, c32 = dl & 31;
            *(bf16x8*)(dst + (size_t)(lw * 12 + h) * 4608 + n * 32 + c32) = v;
        }
    } else {
        // V: transpose via LDS column reads (64 consecutive d/wave = conflict-free),
        // 16B stores of 8 consecutive tokens into VT [d][n]
        int db0 = (nb - 6) * 128;
        #pragma unroll
        for (int it = 0; it < 8; ++it) {
            int item = tid + it * 256;            // 0..2047
            int dl = item & 127;                  // lane-consecutive d
            int nc = item >> 7;                   // 8-token chunk (never crosses window)
            int gr0 = mb * 128 + nc * 8;
            int lw = gr0 / 144, n0 = gr0 - lw * 144;
            int rr = db0 + dl;
            int h = rr >> 5, j32 = rr & 31;
            bf16x8 v;
            #pragma unroll
            for (int q = 0; q < 8; ++q)
                v[q] = sm.tile[(nc * 8 + q) * S + dl];
            *(bf16x8*)(VTp + (size_t)(lw * 12 + h) * 4608 + j32 * 144 + n0) = v;
        }
    }
}

// ------------------------------------------------------------------
// Kernel 2: attention per (window, head). 576 threads = 9 waves.
// ------------------------------------------------------------------
__global__ __launch_bounds__(576) void k_attn(const bf16_t* __restrict__ Qp,
                                              const bf16_t* __restrict__ Kp,
                                              const bf16_t* __restrict__ VTp,
                                              const float* __restrict__ mask,
                                              float* __restrict__ out,
                                              int w0)
{
    extern __shared__ char smem[];
    bf16_t* qb  = (bf16_t*)smem;          // [144][56]
    bf16_t* kb  = qb + 144 * 56;          // [144][56]
    bf16_t* vtb = kb + 144 * 56;          // [32][184]
    bf16_t* pb  = vtb + 32 * 184;         // [144][184]

    int bw = blockIdx.x / 12, h = blockIdx.x % 12;
    int W = w0 + bw;
    size_t base = (size_t)(bw * 12 + h) * 4608;
    int tid = threadIdx.x;

    {
        int row = tid >> 2, c8 = (tid & 3) * 8;
        *(uint4*)&qb[row * 56 + c8] = *(const uint4*)(Qp + base + row * 32 + c8);
        *(uint4*)&kb[row * 56 + c8] = *(const uint4*)(Kp + base + row * 32 + c8);
        int j = tid / 18, seg = tid % 18;
        *(uint4*)&vtb[j * 184 + seg * 8] = *(const uint4*)(VTp + base + j * 144 + seg * 8);
        if (tid < 64) {
            int jj = tid >> 1, cc = 144 + (tid & 1) * 8;
            uint4 z = {0, 0, 0, 0};
            *(uint4*)&vtb[jj * 184 + cc] = z;
        }
    }
    __syncthreads();

    int lane = tid & 63, wv = tid >> 6;
    int l15 = lane & 15, l4 = lane >> 4;
    int row16 = wv * 16;
    const f32x4 fzero = {0.f, 0.f, 0.f, 0.f};

    bf16x8 aq = *(const bf16x8*)&qb[(row16 + l15) * 56 + l4 * 8];
    f32x4 s[9];
    #pragma unroll
    for (int nt = 0; nt < 9; ++nt) {
        bf16x8 bk = *(const bf16x8*)&kb[(nt * 16 + l15) * 56 + l4 * 8];
        s[nt] = __builtin_amdgcn_mfma_f32_16x16x32_bf16(aq, bk, fzero, 0, 0, 0);
    }
    const float* mrow = mask + (size_t)(W % MASKW) * (144 * 144);
    #pragma unroll
    for (int nt = 0; nt < 9; ++nt)
        #pragma unroll
        for (int r = 0; r < 4; ++r)
            s[nt][r] += mrow[(row16 + l4 * 4 + r) * 144 + nt * 16 + l15];

    float mx[4], sm[4];
    #pragma unroll
    for (int r = 0; r < 4; ++r) {
        float m = s[0][r];
        #pragma unroll
        for (int nt = 1; nt < 9; ++nt) m = fmaxf(m, s[nt][r]);
        #pragma unroll
        for (int off = 1; off < 16; off <<= 1) m = fmaxf(m, __shfl_xor(m, off, 64));
        mx[r] = m;
    }
    #pragma unroll
    for (int r = 0; r < 4; ++r) {
        float sum = 0.f;
        #pragma unroll
        for (int nt = 0; nt < 9; ++nt) {
            float e = __expf(s[nt][r] - mx[r]);
            s[nt][r] = e;
            sum += e;
        }
        #pragma unroll
        for (int off = 1; off < 16; off <<= 1) sum += __shfl_xor(sum, off, 64);
        sm[r] = sum;
    }

    #pragma unroll
    for (int nt = 0; nt < 9; ++nt)
        #pragma unroll
        for (int r = 0; r < 4; ++r)
            pb[(row16 + l4 * 4 + r) * 184 + nt * 16 + l15] = (bf16_t)s[nt][r];
    {
        int rr = lane >> 2, cc = 144 + (lane & 3) * 4;
        uint2 z = {0, 0};
        *(uint2*)&pb[(row16 + rr) * 184 + cc] = z;
    }
    f32x4 o0 = {0.f, 0.f, 0.f, 0.f}, o1 = {0.f, 0.f, 0.f, 0.f};
    #pragma unroll
    for (int ks = 0; ks < 5; ++ks) {
        bf16x8 ap  = *(const bf16x8*)&pb[(row16 + l15) * 184 + ks * 32 + l4 * 8];
        bf16x8 bv0 = *(const bf16x8*)&vtb[(l15) * 184 + ks * 32 + l4 * 8];
        bf16x8 bv1 = *(const bf16x8*)&vtb[(16 + l15) * 184 + ks * 32 + l4 * 8];
        o0 = __builtin_amdgcn_mfma_f32_16x16x32_bf16(ap, bv0, o0, 0, 0, 0);
        o1 = __builtin_amdgcn_mfma_f32_16x16x32_bf16(ap, bv1, o1, 0, 0, 0);
    }
    float inv[4];
    #pragma unroll
    for (int r = 0; r < 4; ++r) inv[r] = 1.0f / sm[r];
    size_t orow0 = (size_t)W * 144;
    #pragma unroll
    for (int r = 0; r < 4; ++r) {
        size_t o = (orow0 + row16 + l4 * 4 + r) * 384 + h * 32;
        out[o + l15]      = o0[r] * inv[r];
        out[o + 16 + l15] = o1[r] * inv[r];
    }
}

// ------------------------------------------------------------------
// Kernel 3: proj GEMM, in-place on d_out. Block = 128 rows x full N=384.
// ------------------------------------------------------------------
__global__ __launch_bounds__(512) void k_proj(float* __restrict__ out,
                                              const bf16_t* __restrict__ wp,
                                              const float* __restrict__ bias)
{
    __shared__ bf16_t As[128][56];   // 14,336 B
    __shared__ bf16_t Bs[384][56];   // 43,008 B

    int tid = threadIdx.x;
    int lane = tid & 63, wid = tid >> 6;
    int l15 = lane & 15, l4 = lane >> 4;
    size_t row0 = (size_t)blockIdx.x * 128;

    f32x4 acc[24] = {};

    for (int kk = 0; kk < 12; ++kk) {
        #pragma unroll
        for (int p = 0; p < 2; ++p) {
            int i2 = tid + p * 512;
            int row = i2 >> 3, kq = i2 & 7;
            float4 v = *(const float4*)(out + (row0 + row) * 384 + kk * 32 + kq * 4);
            bf16x4 o = {(bf16_t)v.x, (bf16_t)v.y, (bf16_t)v.z, (bf16_t)v.w};
            *(bf16x4*)&As[row][kq * 4] = o;
        }
        #pragma unroll
        for (int p = 0; p < 3; ++p) {
            int i2 = tid + p * 512;
            int row = i2 >> 2, c8 = (i2 & 3) * 8;
            uint4 v = *(const uint4*)(wp + (size_t)row * 384 + kk * 32 + c8);
            *(uint4*)&Bs[row][c8] = v;
        }
        __syncthreads();
        bf16x8 a = *(const bf16x8*)&As[wid * 16 + l15][l4 * 8];
        #pragma unroll
        for (int j = 0; j < 24; ++j) {
            bf16x8 b = *(const bf16x8*)&Bs[j * 16 + l15][l4 * 8];
            acc[j] = __builtin_amdgcn_mfma_f32_16x16x32_bf16(a, b, acc[j], 0, 0, 0);
        }
        __syncthreads();
    }
    #pragma unroll
    for (int j = 0; j < 24; ++j) {
        int col = j * 16 + l15;
        float bv = bias[col];
        #pragma unroll
        for (int r = 0; r < 4; ++r) {
            size_t row = row0 + wid * 16 + l4 * 4 + r;
            out[row * 384 + col] = acc[j][r] + bv;
        }
    }
}

// ------------------------------------------------------------------
extern "C" void kernel_launch(void* const* d_in, const int* in_sizes, int n_in,
                              void* d_out, int out_size, void* d_ws, size_t ws_size,
                              hipStream_t stream)
{
    const float* x     = (const float*)d_in[0];
    const float* mask  = (const float*)d_in[1];
    const float* qkvw  = (const float*)d_in[2];
    const float* qkvb  = (const float*)d_in[3];
    const float* projw = (const float*)d_in[4];
    const float* projb = (const float*)d_in[5];
    float* out = (float*)d_out;

    char* ws = (char*)d_ws;
    bf16_t* WQ = (bf16_t*)ws;                       // qkv_w bf16: 884,736 B
    bf16_t* WP = (bf16_t*)(ws + 884736);            // proj_w bf16: 294,912 B
    char* chunkbase = ws + 1179648;

    // per-window bytes: xb + Q + K + VT (all bf16) = 4 * 110,592
    size_t avail = ws_size > 1179648 ? ws_size - 1179648 : 0;
    long cw = (long)(avail / 442368);
    cw = (cw / 16) * 16;                            // 16 windows = 2304 rows = 9*256
    if (cw > NWIN) cw = NWIN;
    if (cw < 16) cw = 16;

    size_t qbytes = (size_t)cw * 110592;
    bf16_t* Xb  = (bf16_t*)chunkbase;
    bf16_t* Qp  = (bf16_t*)(chunkbase + qbytes);
    bf16_t* Kp  = (bf16_t*)(chunkbase + 2 * qbytes);
    bf16_t* VTp = (bf16_t*)(chunkbase + 3 * qbytes);

    kconv<<<576, 256, 0, stream>>>(qkvw, projw, WQ, WP);

    for (int w0 = 0; w0 < NWIN; w0 += (int)cw) {
        int c = (int)((NWIN - w0) < cw ? (NWIN - w0) : cw);
        int n8 = c * 6912;                        // bf16x8 groups in chunk
        kx<<<(n8 + 255) / 256, 256, 0, stream>>>(x + (size_t)w0 * 144 * 384, Xb, n8);
        int mblocks = (c * 144) / 128;
        k_qkv<<<mblocks * 9, 256, 0, stream>>>(Xb, WQ, qkvb, Qp, Kp, VTp);
        k_attn<<<c * 12, 576, 97024, stream>>>(Qp, Kp, VTp, mask, out, w0);
    }
    k_proj<<<NWIN * 144 / 128, 512, 0, stream>>>(out, WP, projb);
}

// Round 4
// 805.089 us; speedup vs baseline: 1.2710x; 1.0206x over previous
//
#include <hip/hip_runtime.h>
#include <stdint.h>

// ---- problem constants ----
#define TOK 144        // tokens per window
#define CD  384        // channels
#define NH  12         // heads
#define HDIM 32        // head dim
#define NWIN 1152      // total windows (B*nW)
#define MASKW 144      // mask windows (window index mod 144)
#define NQKV 1152      // 3*C

typedef __bf16 bf16_t;
typedef __bf16 bf16x4 __attribute__((ext_vector_type(4)));
typedef __bf16 bf16x8 __attribute__((ext_vector_type(8)));
typedef float  f32x4  __attribute__((ext_vector_type(4)));

// async global->LDS, 16B per lane. LDS dest is wave-uniform base + lane*16.
__device__ __forceinline__ void gload16(const void* g, void* l) {
    __builtin_amdgcn_global_load_lds(
        (const __attribute__((address_space(1))) uint32_t*)g,
        (__attribute__((address_space(3))) uint32_t*)l, 16, 0, 0);
}

// ------------------------------------------------------------------
// Kernel W: convert qkv_w (1152x384) and proj_w (384x384) to bf16.
// ------------------------------------------------------------------
__global__ __launch_bounds__(256) void kconv(const float* __restrict__ qkvw,
                                             const float* __restrict__ projw,
                                             bf16_t* __restrict__ wq,
                                             bf16_t* __restrict__ wp)
{
    int i = (blockIdx.x * 256 + threadIdx.x) * 4;
    const int NQ = NQKV * CD;   // 442368
    if (i < NQ) {
        float4 v = *(const float4*)(qkvw + i);
        bf16x4 o = {(bf16_t)v.x, (bf16_t)v.y, (bf16_t)v.z, (bf16_t)v.w};
        *(bf16x4*)(wq + i) = o;
    } else {
        int j = i - NQ;
        if (j < CD * CD) {
            float4 v = *(const float4*)(projw + j);
            bf16x4 o = {(bf16_t)v.x, (bf16_t)v.y, (bf16_t)v.z, (bf16_t)v.w};
            *(bf16x4*)(wp + j) = o;
        }
    }
}

// ------------------------------------------------------------------
// Kernel X: convert a chunk of x (fp32) to bf16, 8 elems/thread.
// ------------------------------------------------------------------
__global__ __launch_bounds__(256) void kx(const float* __restrict__ x,
                                          bf16_t* __restrict__ xb, int n8)
{
    int i = blockIdx.x * 256 + threadIdx.x;
    if (i < n8) {
        float4 a = *(const float4*)(x + (size_t)i * 8);
        float4 b = *(const float4*)(x + (size_t)i * 8 + 4);
        bf16x8 o = {(bf16_t)a.x, (bf16_t)a.y, (bf16_t)a.z, (bf16_t)a.w,
                    (bf16_t)b.x, (bf16_t)b.y, (bf16_t)b.z, (bf16_t)b.w};
        *(bf16x8*)(xb + (size_t)i * 8) = o;
    }
}

// ------------------------------------------------------------------
// Kernel 1: QKV GEMM (m97 structure). A = xb bf16, B = qkv_w bf16 [d][c].
// 128x128 tile, BK=64, 256 threads. gload16 staging, linear [128][64] LDS.
// Epilogue through LDS tile -> vectorized 16B stores to Q/K/VT.
// ------------------------------------------------------------------
__global__ __launch_bounds__(256) void k_qkv(const bf16_t* __restrict__ xb,
                                             const bf16_t* __restrict__ wB,
                                             const float* __restrict__ bias,
                                             bf16_t* __restrict__ Qp,
                                             bf16_t* __restrict__ Kp,
                                             bf16_t* __restrict__ VTp)
{
    // bijective XCD-chunked swizzle (m204)
    int nwg = gridDim.x;
    int orig = blockIdx.x;
    int q8 = nwg >> 3, r8 = nwg & 7;
    int xcd = orig & 7, idx = orig >> 3;
    int wgid = (xcd < r8 ? xcd * (q8 + 1) : r8 * (q8 + 1) + (xcd - r8) * q8) + idx;
    int mb = wgid / 9, nb = wgid % 9;

    __shared__ union SMem {
        struct { bf16_t A[128 * 64]; bf16_t B[128 * 64]; } st;  // 32 KB staging
        bf16_t tile[128 * 136];                                  // 34,816 B epilogue
    } sm;
    bf16_t* As = sm.st.A;
    bf16_t* Bs = sm.st.B;

    int tid = threadIdx.x;
    int lane = tid & 63, wid = tid >> 6;
    int wr = (wid >> 1) * 64, wc = (wid & 1) * 64;
    int l15 = lane & 15, l4 = lane >> 4;
    int lr8 = lane >> 3, lc8 = lane & 7;     // row-in-8-row-chunk, 16B slot

    f32x4 acc[4][4] = {};

    const size_t arow0 = (size_t)mb * 128;
    const bf16_t* aG = xb + (arow0 + (size_t)(wid * 4) * 8 + lr8) * 384 + lc8 * 8;
    const bf16_t* bG = wB + ((size_t)nb * 128 + (size_t)(wid * 4) * 8 + lr8) * 384 + lc8 * 8;

    for (int kk = 0; kk < 6; ++kk) {
        #pragma unroll
        for (int p = 0; p < 4; ++p)
            gload16(aG + (size_t)p * (8 * 384) + kk * 64, As + (wid * 4 + p) * 512);
        #pragma unroll
        for (int p = 0; p < 4; ++p)
            gload16(bG + (size_t)p * (8 * 384) + kk * 64, Bs + (wid * 4 + p) * 512);
        __syncthreads();

        #pragma unroll
        for (int kh = 0; kh < 2; ++kh) {
            bf16x8 af[4], bfr[4];
            #pragma unroll
            for (int i = 0; i < 4; ++i)
                af[i] = *(const bf16x8*)&As[(wr + i * 16 + l15) * 64 + kh * 32 + l4 * 8];
            #pragma unroll
            for (int j = 0; j < 4; ++j)
                bfr[j] = *(const bf16x8*)&Bs[(wc + j * 16 + l15) * 64 + kh * 32 + l4 * 8];
            #pragma unroll
            for (int i = 0; i < 4; ++i)
                #pragma unroll
                for (int j = 0; j < 4; ++j)
                    acc[i][j] = __builtin_amdgcn_mfma_f32_16x16x32_bf16(af[i], bfr[j], acc[i][j], 0, 0, 0);
        }
        __syncthreads();
    }

    // ---- epilogue: acc (+bias, q-scale) -> LDS tile -> vectorized stores ----
    const int S = 136;
    const float SCALE = 0.17677669529663687f;            // 1/sqrt(32)
    float scl = (nb < 3) ? SCALE : 1.0f;
    float bv[4];
    #pragma unroll
    for (int j = 0; j < 4; ++j) bv[j] = bias[nb * 128 + wc + j * 16 + l15];

    #pragma unroll
    for (int i = 0; i < 4; ++i)
        #pragma unroll
        for (int j = 0; j < 4; ++j)
            #pragma unroll
            for (int r = 0; r < 4; ++r)
                sm.tile[(wr + i * 16 + l4 * 4 + r) * S + wc + j * 16 + l15] =
                    (bf16_t)((acc[i][j][r] + bv[j]) * scl);
    __syncthreads();

    if (nb < 6) {
        bf16_t* dst = (nb < 3) ? Qp : Kp;
        int db0 = (nb % 3) * 128;
        #pragma unroll
        for (int it = 0; it < 8; ++it) {
            int item = tid + it * 256;
            int row = item >> 4, ch = item & 15;
            bf16x8 v = *(const bf16x8*)&sm.tile[row * S + ch * 8];
            int gr = mb * 128 + row;
            int lw = gr / 144, n = gr - lw * 144;
            int dl = db0 + ch * 8;
            int h = dl >> 5, c32 = dl & 31;
            *(bf16x8*)(dst + (size_t)(lw * 12 + h) * 4608 + n * 32 + c32) = v;
        }
    } else {
        int db0 = (nb - 6) * 128;
        #pragma unroll
        for (int it = 0; it < 8; ++it) {
            int item = tid + it * 256;
            int dl = item & 127;
            int nc = item >> 7;
            int gr0 = mb * 128 + nc * 8;
            int lw = gr0 / 144, n0 = gr0 - lw * 144;
            int rr = db0 + dl;
            int h = rr >> 5, j32 = rr & 31;
            bf16x8 v;
            #pragma unroll
            for (int q = 0; q < 8; ++q)
                v[q] = sm.tile[(nc * 8 + q) * S + dl];
            *(bf16x8*)(VTp + (size_t)(lw * 12 + h) * 4608 + j32 * 144 + n0) = v;
        }
    }
}

// ------------------------------------------------------------------
// Kernel 2: attention per (window, head). 576 threads = 9 waves.
// LDS 70,656 B -> 2 blocks/CU. Q loaded direct from global (no stage).
// Output: bf16 attn_out (chunk-local), via per-wave LDS bounce, 16B stores.
// ------------------------------------------------------------------
__global__ __launch_bounds__(576) void k_attn(const bf16_t* __restrict__ Qp,
                                              const bf16_t* __restrict__ Kp,
                                              const bf16_t* __restrict__ VTp,
                                              const float* __restrict__ mask,
                                              bf16_t* __restrict__ ao,
                                              int w0)
{
    extern __shared__ char smem[];
    bf16_t* kb  = (bf16_t*)smem;          // [144][40]  11,520 B
    bf16_t* vtb = kb + 144 * 40;          // [32][168]  10,752 B
    bf16_t* pb  = vtb + 32 * 168;         // [144][168] 48,384 B

    int bw = blockIdx.x / 12, h = blockIdx.x % 12;
    int W = w0 + bw;
    size_t base = (size_t)(bw * 12 + h) * 4608;
    int tid = threadIdx.x;

    // stage k (stride 40), vt (stride 168, zero-pad cols 144..159)
    {
        int row = tid >> 2, c8 = (tid & 3) * 8;
        *(uint4*)&kb[row * 40 + c8] = *(const uint4*)(Kp + base + row * 32 + c8);
        int j = tid / 18, seg = tid % 18;
        *(uint4*)&vtb[j * 168 + seg * 8] = *(const uint4*)(VTp + base + j * 144 + seg * 8);
        if (tid < 64) {
            int jj = tid >> 1, cc = 144 + (tid & 1) * 8;
            uint4 z = {0, 0, 0, 0};
            *(uint4*)&vtb[jj * 168 + cc] = z;
        }
    }
    __syncthreads();

    int lane = tid & 63, wv = tid >> 6;
    int l15 = lane & 15, l4 = lane >> 4;
    int row16 = wv * 16;
    const f32x4 fzero = {0.f, 0.f, 0.f, 0.f};

    // Q fragment direct from global (wave-contiguous 1 KB)
    bf16x8 aq = *(const bf16x8*)(Qp + base + (row16 + l15) * 32 + l4 * 8);
    f32x4 s[9];
    #pragma unroll
    for (int nt = 0; nt < 9; ++nt) {
        bf16x8 bk = *(const bf16x8*)&kb[(nt * 16 + l15) * 40 + l4 * 8];
        s[nt] = __builtin_amdgcn_mfma_f32_16x16x32_bf16(aq, bk, fzero, 0, 0, 0);
    }
    const float* mrow = mask + (size_t)(W % MASKW) * (144 * 144);
    #pragma unroll
    for (int nt = 0; nt < 9; ++nt)
        #pragma unroll
        for (int r = 0; r < 4; ++r)
            s[nt][r] += mrow[(row16 + l4 * 4 + r) * 144 + nt * 16 + l15];

    float mx[4], sm[4];
    #pragma unroll
    for (int r = 0; r < 4; ++r) {
        float m = s[0][r];
        #pragma unroll
        for (int nt = 1; nt < 9; ++nt) m = fmaxf(m, s[nt][r]);
        #pragma unroll
        for (int off = 1; off < 16; off <<= 1) m = fmaxf(m, __shfl_xor(m, off, 64));
        mx[r] = m;
    }
    #pragma unroll
    for (int r = 0; r < 4; ++r) {
        float sum = 0.f;
        #pragma unroll
        for (int nt = 0; nt < 9; ++nt) {
            float e = __expf(s[nt][r] - mx[r]);
            s[nt][r] = e;
            sum += e;
        }
        #pragma unroll
        for (int off = 1; off < 16; off <<= 1) sum += __shfl_xor(sum, off, 64);
        sm[r] = sum;
    }

    // P (unnormalized bf16) -> this wave's pb rows; zero-pad cols 144..159
    #pragma unroll
    for (int nt = 0; nt < 9; ++nt)
        #pragma unroll
        for (int r = 0; r < 4; ++r)
            pb[(row16 + l4 * 4 + r) * 168 + nt * 16 + l15] = (bf16_t)s[nt][r];
    {
        int rr = lane >> 2, cc = 144 + (lane & 3) * 4;
        uint2 z = {0, 0};
        *(uint2*)&pb[(row16 + rr) * 168 + cc] = z;
    }
    // PV (same-wave LDS, no barrier)
    f32x4 o0 = {0.f, 0.f, 0.f, 0.f}, o1 = {0.f, 0.f, 0.f, 0.f};
    #pragma unroll
    for (int ks = 0; ks < 5; ++ks) {
        bf16x8 ap  = *(const bf16x8*)&pb[(row16 + l15) * 168 + ks * 32 + l4 * 8];
        bf16x8 bv0 = *(const bf16x8*)&vtb[(l15) * 168 + ks * 32 + l4 * 8];
        bf16x8 bv1 = *(const bf16x8*)&vtb[(16 + l15) * 168 + ks * 32 + l4 * 8];
        o0 = __builtin_amdgcn_mfma_f32_16x16x32_bf16(ap, bv0, o0, 0, 0, 0);
        o1 = __builtin_amdgcn_mfma_f32_16x16x32_bf16(ap, bv1, o1, 0, 0, 0);
    }
    // normalize, bf16, bounce through this wave's (dead) pb rows, 16B stores
    float inv[4];
    #pragma unroll
    for (int r = 0; r < 4; ++r) inv[r] = 1.0f / sm[r];
    bf16_t* ob = pb + row16 * 168;   // [16][32] dense
    #pragma unroll
    for (int r = 0; r < 4; ++r) {
        ob[(l4 * 4 + r) * 32 + l15]      = (bf16_t)(o0[r] * inv[r]);
        ob[(l4 * 4 + r) * 32 + 16 + l15] = (bf16_t)(o1[r] * inv[r]);
    }
    bf16x8 v = *(const bf16x8*)&ob[(lane >> 2) * 32 + (lane & 3) * 8];
    *(bf16x8*)(ao + ((size_t)bw * 144 + row16 + (lane >> 2)) * 384 + h * 32 + (lane & 3) * 8) = v;
}

// ------------------------------------------------------------------
// Kernel 3: proj GEMM (m97 structure). A = attn_out bf16 (gload16 staged),
// B = proj_w bf16 [d][c]. 128x128 tile, BK=64. fp32 out via 2-pass LDS tile.
// ------------------------------------------------------------------
__global__ __launch_bounds__(256) void k_proj(const bf16_t* __restrict__ ao,
                                              const bf16_t* __restrict__ wp,
                                              const float* __restrict__ bias,
                                              float* __restrict__ out,
                                              int rowoff)
{
    int nwg = gridDim.x;
    int orig = blockIdx.x;
    int q8 = nwg >> 3, r8 = nwg & 7;
    int xcd = orig & 7, idx = orig >> 3;
    int wgid = (xcd < r8 ? xcd * (q8 + 1) : r8 * (q8 + 1) + (xcd - r8) * q8) + idx;
    int mb = wgid / 3, nb = wgid % 3;

    __shared__ union SMem {
        struct { bf16_t A[128 * 64]; bf16_t B[128 * 64]; } st;  // 32 KB
        float tile[128 * 68];                                    // 34,816 B
    } sm;
    bf16_t* As = sm.st.A;
    bf16_t* Bs = sm.st.B;

    int tid = threadIdx.x;
    int lane = tid & 63, wid = tid >> 6;
    int wr = (wid >> 1) * 64, wc = (wid & 1) * 64;
    int l15 = lane & 15, l4 = lane >> 4;
    int lr8 = lane >> 3, lc8 = lane & 7;

    f32x4 acc[4][4] = {};

    const bf16_t* aG = ao + ((size_t)mb * 128 + (size_t)(wid * 4) * 8 + lr8) * 384 + lc8 * 8;
    const bf16_t* bG = wp + ((size_t)nb * 128 + (size_t)(wid * 4) * 8 + lr8) * 384 + lc8 * 8;

    for (int kk = 0; kk < 6; ++kk) {
        #pragma unroll
        for (int p = 0; p < 4; ++p)
            gload16(aG + (size_t)p * (8 * 384) + kk * 64, As + (wid * 4 + p) * 512);
        #pragma unroll
        for (int p = 0; p < 4; ++p)
            gload16(bG + (size_t)p * (8 * 384) + kk * 64, Bs + (wid * 4 + p) * 512);
        __syncthreads();

        #pragma unroll
        for (int kh = 0; kh < 2; ++kh) {
            bf16x8 af[4], bfr[4];
            #pragma unroll
            for (int i = 0; i < 4; ++i)
                af[i] = *(const bf16x8*)&As[(wr + i * 16 + l15) * 64 + kh * 32 + l4 * 8];
            #pragma unroll
            for (int j = 0; j < 4; ++j)
                bfr[j] = *(const bf16x8*)&Bs[(wc + j * 16 + l15) * 64 + kh * 32 + l4 * 8];
            #pragma unroll
            for (int i = 0; i < 4; ++i)
                #pragma unroll
                for (int j = 0; j < 4; ++j)
                    acc[i][j] = __builtin_amdgcn_mfma_f32_16x16x32_bf16(af[i], bfr[j], acc[i][j], 0, 0, 0);
        }
        __syncthreads();
    }

    // epilogue: two passes (wave-column halves) through fp32 [128][68] tile
    float bv[4];
    #pragma unroll
    for (int j = 0; j < 4; ++j) bv[j] = bias[nb * 128 + wc + j * 16 + l15];

    #pragma unroll
    for (int half = 0; half < 2; ++half) {
        if (half) __syncthreads();
        if ((wid & 1) == half) {
            #pragma unroll
            for (int i = 0; i < 4; ++i)
                #pragma unroll
                for (int j = 0; j < 4; ++j)
                    #pragma unroll
                    for (int r = 0; r < 4; ++r)
                        sm.tile[(wr + i * 16 + l4 * 4 + r) * 68 + j * 16 + l15] =
                            acc[i][j][r] + bv[j];
        }
        __syncthreads();
        #pragma unroll
        for (int it = 0; it < 8; ++it) {
            int item = tid + it * 256;            // 0..2047 = 128 rows x 16 f4
            int row = item >> 4, ch = item & 15;
            float4 v = *(const float4*)&sm.tile[row * 68 + ch * 4];
            *(float4*)(out + (size_t)(rowoff + mb * 128 + row) * 384
                           + nb * 128 + half * 64 + ch * 4) = v;
        }
    }
}

// ------------------------------------------------------------------
extern "C" void kernel_launch(void* const* d_in, const int* in_sizes, int n_in,
                              void* d_out, int out_size, void* d_ws, size_t ws_size,
                              hipStream_t stream)
{
    const float* x     = (const float*)d_in[0];
    const float* mask  = (const float*)d_in[1];
    const float* qkvw  = (const float*)d_in[2];
    const float* qkvb  = (const float*)d_in[3];
    const float* projw = (const float*)d_in[4];
    const float* projb = (const float*)d_in[5];
    float* out = (float*)d_out;

    char* ws = (char*)d_ws;
    bf16_t* WQ = (bf16_t*)ws;                       // qkv_w bf16: 884,736 B
    bf16_t* WP = (bf16_t*)(ws + 884736);            // proj_w bf16: 294,912 B
    char* chunkbase = ws + 1179648;

    // per-window bytes: xb + Q + K + VT + attn_out (all bf16) = 5 * 110,592
    size_t avail = ws_size > 1179648 ? ws_size - 1179648 : 0;
    long cw = (long)(avail / 552960);
    cw = (cw / 16) * 16;                            // 16 windows = 2304 rows (÷128 ok)
    if (cw > NWIN) cw = NWIN;
    if (cw < 16) cw = 16;

    size_t qbytes = (size_t)cw * 110592;
    bf16_t* Xb  = (bf16_t*)chunkbase;
    bf16_t* Qp  = (bf16_t*)(chunkbase + qbytes);
    bf16_t* Kp  = (bf16_t*)(chunkbase + 2 * qbytes);
    bf16_t* VTp = (bf16_t*)(chunkbase + 3 * qbytes);
    bf16_t* AO  = (bf16_t*)(chunkbase + 4 * qbytes);

    kconv<<<576, 256, 0, stream>>>(qkvw, projw, WQ, WP);

    for (int w0 = 0; w0 < NWIN; w0 += (int)cw) {
        int c = (int)((NWIN - w0) < cw ? (NWIN - w0) : cw);
        int n8 = c * 6912;
        kx<<<(n8 + 255) / 256, 256, 0, stream>>>(x + (size_t)w0 * 144 * 384, Xb, n8);
        int mblocks = (c * 144) / 128;
        k_qkv<<<mblocks * 9, 256, 0, stream>>>(Xb, WQ, qkvb, Qp, Kp, VTp);
        k_attn<<<c * 12, 576, 70656, stream>>>(Qp, Kp, VTp, mask, AO, w0);
        k_proj<<<mblocks * 3, 256, 0, stream>>>(AO, WP, projb, out, w0 * 144);
    }
}

// Round 5
// 661.075 us; speedup vs baseline: 1.5479x; 1.2178x over previous
//
#include <hip/hip_runtime.h>
#include <stdint.h>

// ---- problem constants ----
#define TOK 144        // tokens per window
#define CD  384        // channels
#define NH  12         // heads
#define HDIM 32        // head dim
#define NWIN 1152      // total windows (B*nW)
#define MASKW 144      // mask windows (window index mod 144)
#define NQKV 1152      // 3*C

typedef __bf16 bf16_t;
typedef __bf16 bf16x4 __attribute__((ext_vector_type(4)));
typedef __bf16 bf16x8 __attribute__((ext_vector_type(8)));
typedef float  f32x4  __attribute__((ext_vector_type(4)));

// async global->LDS, 16B per lane. LDS dest is wave-uniform base + lane*16.
__device__ __forceinline__ void gload16(const void* g, void* l) {
    __builtin_amdgcn_global_load_lds(
        (const __attribute__((address_space(1))) uint32_t*)g,
        (__attribute__((address_space(3))) uint32_t*)l, 16, 0, 0);
}

// ------------------------------------------------------------------
// Kernel W: convert qkv_w (1152x384) and proj_w (384x384) to bf16.
// ------------------------------------------------------------------
__global__ __launch_bounds__(256) void kconv(const float* __restrict__ qkvw,
                                             const float* __restrict__ projw,
                                             bf16_t* __restrict__ wq,
                                             bf16_t* __restrict__ wp)
{
    int i = (blockIdx.x * 256 + threadIdx.x) * 4;
    const int NQ = NQKV * CD;   // 442368
    if (i < NQ) {
        float4 v = *(const float4*)(qkvw + i);
        bf16x4 o = {(bf16_t)v.x, (bf16_t)v.y, (bf16_t)v.z, (bf16_t)v.w};
        *(bf16x4*)(wq + i) = o;
    } else {
        int j = i - NQ;
        if (j < CD * CD) {
            float4 v = *(const float4*)(projw + j);
            bf16x4 o = {(bf16_t)v.x, (bf16_t)v.y, (bf16_t)v.z, (bf16_t)v.w};
            *(bf16x4*)(wp + j) = o;
        }
    }
}

// ------------------------------------------------------------------
// Kernel M: rearrange mask (144x144x144 fp32) into MFMA C-fragment order:
// maskR[((wm*9 + wv)*9 + nt)*256 + lane*4 + r] =
//     mask[wm][wv*16 + (lane>>4)*4 + r][nt*16 + (lane&15)]
// One float4 per thread; 746,496 float4s total.
// ------------------------------------------------------------------
__global__ __launch_bounds__(256) void kmask(const float* __restrict__ mask,
                                             float* __restrict__ maskR)
{
    int t = blockIdx.x * 256 + threadIdx.x;      // 0..746495
    int lane = t & 63;
    int g = t >> 6;                              // (wm*9+wv)*9+nt
    int nt = g % 9;
    int g2 = g / 9;
    int wv = g2 % 9;
    int wm = g2 / 9;
    const float* src = mask + (size_t)wm * 20736
                     + (wv * 16 + (lane >> 4) * 4) * 144 + nt * 16 + (lane & 15);
    f32x4 v = { src[0], src[144], src[288], src[432] };
    *(f32x4*)(maskR + (size_t)t * 4) = v;
}

// ------------------------------------------------------------------
// Kernel X: convert a chunk of x (fp32) to bf16, 8 elems/thread.
// ------------------------------------------------------------------
__global__ __launch_bounds__(256) void kx(const float* __restrict__ x,
                                          bf16_t* __restrict__ xb, int n8)
{
    int i = blockIdx.x * 256 + threadIdx.x;
    if (i < n8) {
        float4 a = *(const float4*)(x + (size_t)i * 8);
        float4 b = *(const float4*)(x + (size_t)i * 8 + 4);
        bf16x8 o = {(bf16_t)a.x, (bf16_t)a.y, (bf16_t)a.z, (bf16_t)a.w,
                    (bf16_t)b.x, (bf16_t)b.y, (bf16_t)b.z, (bf16_t)b.w};
        *(bf16x8*)(xb + (size_t)i * 8) = o;
    }
}

// ------------------------------------------------------------------
// Kernel 1: QKV GEMM (m97 structure). A = xb bf16, B = qkv_w bf16 [d][c].
// 128x128 tile, BK=64, 256 threads. gload16 staging, linear [128][64] LDS.
// Epilogue through LDS tile -> vectorized 16B stores to Q/K/VT.
// ------------------------------------------------------------------
__global__ __launch_bounds__(256) void k_qkv(const bf16_t* __restrict__ xb,
                                             const bf16_t* __restrict__ wB,
                                             const float* __restrict__ bias,
                                             bf16_t* __restrict__ Qp,
                                             bf16_t* __restrict__ Kp,
                                             bf16_t* __restrict__ VTp)
{
    // bijective XCD-chunked swizzle (m204)
    int nwg = gridDim.x;
    int orig = blockIdx.x;
    int q8 = nwg >> 3, r8 = nwg & 7;
    int xcd = orig & 7, idx = orig >> 3;
    int wgid = (xcd < r8 ? xcd * (q8 + 1) : r8 * (q8 + 1) + (xcd - r8) * q8) + idx;
    int mb = wgid / 9, nb = wgid % 9;

    __shared__ union SMem {
        struct { bf16_t A[128 * 64]; bf16_t B[128 * 64]; } st;  // 32 KB staging
        bf16_t tile[128 * 136];                                  // 34,816 B epilogue
    } sm;
    bf16_t* As = sm.st.A;
    bf16_t* Bs = sm.st.B;

    int tid = threadIdx.x;
    int lane = tid & 63, wid = tid >> 6;
    int wr = (wid >> 1) * 64, wc = (wid & 1) * 64;
    int l15 = lane & 15, l4 = lane >> 4;
    int lr8 = lane >> 3, lc8 = lane & 7;

    f32x4 acc[4][4] = {};

    const size_t arow0 = (size_t)mb * 128;
    const bf16_t* aG = xb + (arow0 + (size_t)(wid * 4) * 8 + lr8) * 384 + lc8 * 8;
    const bf16_t* bG = wB + ((size_t)nb * 128 + (size_t)(wid * 4) * 8 + lr8) * 384 + lc8 * 8;

    for (int kk = 0; kk < 6; ++kk) {
        #pragma unroll
        for (int p = 0; p < 4; ++p)
            gload16(aG + (size_t)p * (8 * 384) + kk * 64, As + (wid * 4 + p) * 512);
        #pragma unroll
        for (int p = 0; p < 4; ++p)
            gload16(bG + (size_t)p * (8 * 384) + kk * 64, Bs + (wid * 4 + p) * 512);
        __syncthreads();

        #pragma unroll
        for (int kh = 0; kh < 2; ++kh) {
            bf16x8 af[4], bfr[4];
            #pragma unroll
            for (int i = 0; i < 4; ++i)
                af[i] = *(const bf16x8*)&As[(wr + i * 16 + l15) * 64 + kh * 32 + l4 * 8];
            #pragma unroll
            for (int j = 0; j < 4; ++j)
                bfr[j] = *(const bf16x8*)&Bs[(wc + j * 16 + l15) * 64 + kh * 32 + l4 * 8];
            #pragma unroll
            for (int i = 0; i < 4; ++i)
                #pragma unroll
                for (int j = 0; j < 4; ++j)
                    acc[i][j] = __builtin_amdgcn_mfma_f32_16x16x32_bf16(af[i], bfr[j], acc[i][j], 0, 0, 0);
        }
        __syncthreads();
    }

    // ---- epilogue: acc (+bias, q-scale) -> LDS tile -> vectorized stores ----
    const int S = 136;
    const float SCALE = 0.17677669529663687f;            // 1/sqrt(32)
    float scl = (nb < 3) ? SCALE : 1.0f;
    float bv[4];
    #pragma unroll
    for (int j = 0; j < 4; ++j) bv[j] = bias[nb * 128 + wc + j * 16 + l15];

    #pragma unroll
    for (int i = 0; i < 4; ++i)
        #pragma unroll
        for (int j = 0; j < 4; ++j)
            #pragma unroll
            for (int r = 0; r < 4; ++r)
                sm.tile[(wr + i * 16 + l4 * 4 + r) * S + wc + j * 16 + l15] =
                    (bf16_t)((acc[i][j][r] + bv[j]) * scl);
    __syncthreads();

    if (nb < 6) {
        bf16_t* dst = (nb < 3) ? Qp : Kp;
        int db0 = (nb % 3) * 128;
        #pragma unroll
        for (int it = 0; it < 8; ++it) {
            int item = tid + it * 256;
            int row = item >> 4, ch = item & 15;
            bf16x8 v = *(const bf16x8*)&sm.tile[row * S + ch * 8];
            int gr = mb * 128 + row;
            int lw = gr / 144, n = gr - lw * 144;
            int dl = db0 + ch * 8;
            int h = dl >> 5, c32 = dl & 31;
            *(bf16x8*)(dst + (size_t)(lw * 12 + h) * 4608 + n * 32 + c32) = v;
        }
    } else {
        int db0 = (nb - 6) * 128;
        #pragma unroll
        for (int it = 0; it < 8; ++it) {
            int item = tid + it * 256;
            int dl = item & 127;
            int nc = item >> 7;
            int gr0 = mb * 128 + nc * 8;
            int lw = gr0 / 144, n0 = gr0 - lw * 144;
            int rr = db0 + dl;
            int h = rr >> 5, j32 = rr & 31;
            bf16x8 v;
            #pragma unroll
            for (int q = 0; q < 8; ++q)
                v[q] = sm.tile[(nc * 8 + q) * S + dl];
            *(bf16x8*)(VTp + (size_t)(lw * 12 + h) * 4608 + j32 * 144 + n0) = v;
        }
    }
}

// ------------------------------------------------------------------
// Kernel 2: attention per (window, head). 576 threads = 9 waves.
// XCD-swizzled grid (12 heads of a window consecutive on one XCD ->
// mask L2-resident). Mask read as MFMA C-in fragments (maskR), 9 coalesced
// float4 loads/wave. LDS 70,656 B -> 2 blocks/CU.
// ------------------------------------------------------------------
__global__ __launch_bounds__(576) void k_attn(const bf16_t* __restrict__ Qp,
                                              const bf16_t* __restrict__ Kp,
                                              const bf16_t* __restrict__ VTp,
                                              const float* __restrict__ maskR,
                                              bf16_t* __restrict__ ao,
                                              int w0)
{
    extern __shared__ char smem[];
    bf16_t* kb  = (bf16_t*)smem;          // [144][40]  11,520 B
    bf16_t* vtb = kb + 144 * 40;          // [32][168]  10,752 B
    bf16_t* pb  = vtb + 32 * 168;         // [144][168] 48,384 B

    // bijective XCD-chunked swizzle (m204)
    int nwg = gridDim.x;
    int orig = blockIdx.x;
    int q8 = nwg >> 3, r8 = nwg & 7;
    int xcd = orig & 7, idx = orig >> 3;
    int wgid = (xcd < r8 ? xcd * (q8 + 1) : r8 * (q8 + 1) + (xcd - r8) * q8) + idx;

    int bw = wgid / 12, h = wgid % 12;
    int W = w0 + bw;
    int wm = W % MASKW;
    size_t base = (size_t)(bw * 12 + h) * 4608;
    int tid = threadIdx.x;

    // stage k (stride 40), vt (stride 168, zero-pad cols 144..159)
    {
        int row = tid >> 2, c8 = (tid & 3) * 8;
        *(uint4*)&kb[row * 40 + c8] = *(const uint4*)(Kp + base + row * 32 + c8);
        int j = tid / 18, seg = tid % 18;
        *(uint4*)&vtb[j * 168 + seg * 8] = *(const uint4*)(VTp + base + j * 144 + seg * 8);
        if (tid < 64) {
            int jj = tid >> 1, cc = 144 + (tid & 1) * 8;
            uint4 z = {0, 0, 0, 0};
            *(uint4*)&vtb[jj * 168 + cc] = z;
        }
    }
    __syncthreads();

    int lane = tid & 63, wv = tid >> 6;
    int l15 = lane & 15, l4 = lane >> 4;
    int row16 = wv * 16;

    // Q fragment direct from global (wave-contiguous 1 KB)
    bf16x8 aq = *(const bf16x8*)(Qp + base + (row16 + l15) * 32 + l4 * 8);

    // S = q k^T + mask  (mask = MFMA C-in, coalesced fragment loads)
    const float* mR = maskR + ((size_t)(wm * 9 + wv) * 9) * 256 + lane * 4;
    f32x4 s[9];
    #pragma unroll
    for (int nt = 0; nt < 9; ++nt) {
        bf16x8 bk = *(const bf16x8*)&kb[(nt * 16 + l15) * 40 + l4 * 8];
        f32x4 mv = *(const f32x4*)(mR + nt * 256);
        s[nt] = __builtin_amdgcn_mfma_f32_16x16x32_bf16(aq, bk, mv, 0, 0, 0);
    }

    float mx[4], sm[4];
    #pragma unroll
    for (int r = 0; r < 4; ++r) {
        float m = s[0][r];
        #pragma unroll
        for (int nt = 1; nt < 9; ++nt) m = fmaxf(m, s[nt][r]);
        #pragma unroll
        for (int off = 1; off < 16; off <<= 1) m = fmaxf(m, __shfl_xor(m, off, 64));
        mx[r] = m;
    }
    #pragma unroll
    for (int r = 0; r < 4; ++r) {
        float sum = 0.f;
        #pragma unroll
        for (int nt = 0; nt < 9; ++nt) {
            float e = __expf(s[nt][r] - mx[r]);
            s[nt][r] = e;
            sum += e;
        }
        #pragma unroll
        for (int off = 1; off < 16; off <<= 1) sum += __shfl_xor(sum, off, 64);
        sm[r] = sum;
    }

    // P (unnormalized bf16) -> this wave's pb rows; zero-pad cols 144..159
    #pragma unroll
    for (int nt = 0; nt < 9; ++nt)
        #pragma unroll
        for (int r = 0; r < 4; ++r)
            pb[(row16 + l4 * 4 + r) * 168 + nt * 16 + l15] = (bf16_t)s[nt][r];
    {
        int rr = lane >> 2, cc = 144 + (lane & 3) * 4;
        uint2 z = {0, 0};
        *(uint2*)&pb[(row16 + rr) * 168 + cc] = z;
    }
    // PV (same-wave LDS, no barrier)
    f32x4 o0 = {0.f, 0.f, 0.f, 0.f}, o1 = {0.f, 0.f, 0.f, 0.f};
    #pragma unroll
    for (int ks = 0; ks < 5; ++ks) {
        bf16x8 ap  = *(const bf16x8*)&pb[(row16 + l15) * 168 + ks * 32 + l4 * 8];
        bf16x8 bv0 = *(const bf16x8*)&vtb[(l15) * 168 + ks * 32 + l4 * 8];
        bf16x8 bv1 = *(const bf16x8*)&vtb[(16 + l15) * 168 + ks * 32 + l4 * 8];
        o0 = __builtin_amdgcn_mfma_f32_16x16x32_bf16(ap, bv0, o0, 0, 0, 0);
        o1 = __builtin_amdgcn_mfma_f32_16x16x32_bf16(ap, bv1, o1, 0, 0, 0);
    }
    // normalize, bf16, bounce through this wave's (dead) pb rows, 16B stores
    float inv[4];
    #pragma unroll
    for (int r = 0; r < 4; ++r) inv[r] = 1.0f / sm[r];
    bf16_t* ob = pb + row16 * 168;   // [16][32] dense
    #pragma unroll
    for (int r = 0; r < 4; ++r) {
        ob[(l4 * 4 + r) * 32 + l15]      = (bf16_t)(o0[r] * inv[r]);
        ob[(l4 * 4 + r) * 32 + 16 + l15] = (bf16_t)(o1[r] * inv[r]);
    }
    bf16x8 v = *(const bf16x8*)&ob[(lane >> 2) * 32 + (lane & 3) * 8];
    *(bf16x8*)(ao + ((size_t)bw * 144 + row16 + (lane >> 2)) * 384 + h * 32 + (lane & 3) * 8) = v;
}

// ------------------------------------------------------------------
// Kernel 3: proj GEMM (m97 structure). A = attn_out bf16 (gload16 staged),
// B = proj_w bf16 [d][c]. 128x128 tile, BK=64. fp32 out via 2-pass LDS tile.
// ------------------------------------------------------------------
__global__ __launch_bounds__(256) void k_proj(const bf16_t* __restrict__ ao,
                                              const bf16_t* __restrict__ wp,
                                              const float* __restrict__ bias,
                                              float* __restrict__ out,
                                              int rowoff)
{
    int nwg = gridDim.x;
    int orig = blockIdx.x;
    int q8 = nwg >> 3, r8 = nwg & 7;
    int xcd = orig & 7, idx = orig >> 3;
    int wgid = (xcd < r8 ? xcd * (q8 + 1) : r8 * (q8 + 1) + (xcd - r8) * q8) + idx;
    int mb = wgid / 3, nb = wgid % 3;

    __shared__ union SMem {
        struct { bf16_t A[128 * 64]; bf16_t B[128 * 64]; } st;  // 32 KB
        float tile[128 * 68];                                    // 34,816 B
    } sm;
    bf16_t* As = sm.st.A;
    bf16_t* Bs = sm.st.B;

    int tid = threadIdx.x;
    int lane = tid & 63, wid = tid >> 6;
    int wr = (wid >> 1) * 64, wc = (wid & 1) * 64;
    int l15 = lane & 15, l4 = lane >> 4;
    int lr8 = lane >> 3, lc8 = lane & 7;

    f32x4 acc[4][4] = {};

    const bf16_t* aG = ao + ((size_t)mb * 128 + (size_t)(wid * 4) * 8 + lr8) * 384 + lc8 * 8;
    const bf16_t* bG = wp + ((size_t)nb * 128 + (size_t)(wid * 4) * 8 + lr8) * 384 + lc8 * 8;

    for (int kk = 0; kk < 6; ++kk) {
        #pragma unroll
        for (int p = 0; p < 4; ++p)
            gload16(aG + (size_t)p * (8 * 384) + kk * 64, As + (wid * 4 + p) * 512);
        #pragma unroll
        for (int p = 0; p < 4; ++p)
            gload16(bG + (size_t)p * (8 * 384) + kk * 64, Bs + (wid * 4 + p) * 512);
        __syncthreads();

        #pragma unroll
        for (int kh = 0; kh < 2; ++kh) {
            bf16x8 af[4], bfr[4];
            #pragma unroll
            for (int i = 0; i < 4; ++i)
                af[i] = *(const bf16x8*)&As[(wr + i * 16 + l15) * 64 + kh * 32 + l4 * 8];
            #pragma unroll
            for (int j = 0; j < 4; ++j)
                bfr[j] = *(const bf16x8*)&Bs[(wc + j * 16 + l15) * 64 + kh * 32 + l4 * 8];
            #pragma unroll
            for (int i = 0; i < 4; ++i)
                #pragma unroll
                for (int j = 0; j < 4; ++j)
                    acc[i][j] = __builtin_amdgcn_mfma_f32_16x16x32_bf16(af[i], bfr[j], acc[i][j], 0, 0, 0);
        }
        __syncthreads();
    }

    float bv[4];
    #pragma unroll
    for (int j = 0; j < 4; ++j) bv[j] = bias[nb * 128 + wc + j * 16 + l15];

    #pragma unroll
    for (int half = 0; half < 2; ++half) {
        if (half) __syncthreads();
        if ((wid & 1) == half) {
            #pragma unroll
            for (int i = 0; i < 4; ++i)
                #pragma unroll
                for (int j = 0; j < 4; ++j)
                    #pragma unroll
                    for (int r = 0; r < 4; ++r)
                        sm.tile[(wr + i * 16 + l4 * 4 + r) * 68 + j * 16 + l15] =
                            acc[i][j][r] + bv[j];
        }
        __syncthreads();
        #pragma unroll
        for (int it = 0; it < 8; ++it) {
            int item = tid + it * 256;
            int row = item >> 4, ch = item & 15;
            float4 v = *(const float4*)&sm.tile[row * 68 + ch * 4];
            *(float4*)(out + (size_t)(rowoff + mb * 128 + row) * 384
                           + nb * 128 + half * 64 + ch * 4) = v;
        }
    }
}

// ------------------------------------------------------------------
extern "C" void kernel_launch(void* const* d_in, const int* in_sizes, int n_in,
                              void* d_out, int out_size, void* d_ws, size_t ws_size,
                              hipStream_t stream)
{
    const float* x     = (const float*)d_in[0];
    const float* mask  = (const float*)d_in[1];
    const float* qkvw  = (const float*)d_in[2];
    const float* qkvb  = (const float*)d_in[3];
    const float* projw = (const float*)d_in[4];
    const float* projb = (const float*)d_in[5];
    float* out = (float*)d_out;

    char* ws = (char*)d_ws;
    bf16_t* WQ   = (bf16_t*)ws;                     // qkv_w bf16: 884,736 B
    bf16_t* WP   = (bf16_t*)(ws + 884736);          // proj_w bf16: 294,912 B
    float* maskR = (float*)(ws + 1179648);          // rearranged mask: 11,943,936 B
    char* chunkbase = ws + 13123584;

    // per-window bytes: xb + Q + K + VT + attn_out (all bf16) = 5 * 110,592
    size_t avail = ws_size > 13123584 ? ws_size - 13123584 : 0;
    long cw = (long)(avail / 552960);
    cw = (cw / 16) * 16;
    if (cw > NWIN) cw = NWIN;
    if (cw < 16) cw = 16;

    size_t qbytes = (size_t)cw * 110592;
    bf16_t* Xb  = (bf16_t*)chunkbase;
    bf16_t* Qp  = (bf16_t*)(chunkbase + qbytes);
    bf16_t* Kp  = (bf16_t*)(chunkbase + 2 * qbytes);
    bf16_t* VTp = (bf16_t*)(chunkbase + 3 * qbytes);
    bf16_t* AO  = (bf16_t*)(chunkbase + 4 * qbytes);

    kconv<<<576, 256, 0, stream>>>(qkvw, projw, WQ, WP);
    kmask<<<2916, 256, 0, stream>>>(mask, maskR);

    for (int w0 = 0; w0 < NWIN; w0 += (int)cw) {
        int c = (int)((NWIN - w0) < cw ? (NWIN - w0) : cw);
        int n8 = c * 6912;
        kx<<<(n8 + 255) / 256, 256, 0, stream>>>(x + (size_t)w0 * 144 * 384, Xb, n8);
        int mblocks = (c * 144) / 128;
        k_qkv<<<mblocks * 9, 256, 0, stream>>>(Xb, WQ, qkvb, Qp, Kp, VTp);
        k_attn<<<c * 12, 576, 70656, stream>>>(Qp, Kp, VTp, maskR, AO, w0);
        k_proj<<<mblocks * 3, 256, 0, stream>>>(AO, WP, projb, out, w0 * 144);
    }
}

// Round 7
// 647.557 us; speedup vs baseline: 1.5802x; 1.0209x over previous
//
#include <hip/hip_runtime.h>
#include <stdint.h>

// ---- problem constants ----
#define TOK 144        // tokens per window
#define CD  384        // channels
#define NH  12         // heads
#define HDIM 32        // head dim
#define NWIN 1152      // total windows (B*nW)
#define MASKW 144      // mask windows (window index mod 144)
#define NQKV 1152      // 3*C

typedef __bf16 bf16_t;
typedef __bf16 bf16x4 __attribute__((ext_vector_type(4)));
typedef __bf16 bf16x8 __attribute__((ext_vector_type(8)));
typedef float  f32x4  __attribute__((ext_vector_type(4)));

// async global->LDS, 16B per lane. LDS dest is wave-uniform base + lane*16.
__device__ __forceinline__ void gload16(const void* g, void* l) {
    __builtin_amdgcn_global_load_lds(
        (const __attribute__((address_space(1))) uint32_t*)g,
        (__attribute__((address_space(3))) uint32_t*)l, 16, 0, 0);
}

// ------------------------------------------------------------------
// Kernel P: pack qkv_w and proj_w (fp32 [d][c]) into bf16 MFMA B-fragment
// order. Unit u = (((nb*6+kk)*2+kh)*8 + jj)*64 + lane holds
//   W[nb*128 + jj*16 + (lane&15)][kk*64 + kh*32 + (lane>>4)*8 .. +7]
// jj = 0..7 covers the FULL 128-d block (wave wc picks jj = (wid&1)*4+j).
// Q rows (d<384) pre-scaled by 1/sqrt(32).
// 55296 qkv units + 18432 proj units = 73728 threads (288 blocks).
// ------------------------------------------------------------------
__global__ __launch_bounds__(256) void kpack(const float* __restrict__ qkvw,
                                             const float* __restrict__ projw,
                                             bf16_t* __restrict__ WQf,
                                             bf16_t* __restrict__ WPf)
{
    int t = blockIdx.x * 256 + threadIdx.x;
    const int NQU = 55296;
    const float SCALE = 0.17677669529663687f;   // 1/sqrt(32)
    if (t < NQU) {
        int lane = t & 63;
        int jj = (t >> 6) & 7;
        int kh = (t >> 9) & 1;
        int rest = t >> 10;
        int kk = rest % 6, nb = rest / 6;
        int d = nb * 128 + jj * 16 + (lane & 15);
        int k = kk * 64 + kh * 32 + (lane >> 4) * 8;
        const float* src = qkvw + (size_t)d * 384 + k;
        float4 a = *(const float4*)src;
        float4 b = *(const float4*)(src + 4);
        float s = (d < 384) ? SCALE : 1.0f;
        bf16x8 o = {(bf16_t)(a.x*s), (bf16_t)(a.y*s), (bf16_t)(a.z*s), (bf16_t)(a.w*s),
                    (bf16_t)(b.x*s), (bf16_t)(b.y*s), (bf16_t)(b.z*s), (bf16_t)(b.w*s)};
        *(bf16x8*)(WQf + (size_t)t * 8) = o;
    } else {
        int u = t - NQU;
        int lane = u & 63;
        int jj = (u >> 6) & 7;
        int kh = (u >> 9) & 1;
        int rest = u >> 10;
        int kk = rest % 6, nb = rest / 6;
        int d = nb * 128 + jj * 16 + (lane & 15);
        int k = kk * 64 + kh * 32 + (lane >> 4) * 8;
        const float* src = projw + (size_t)d * 384 + k;
        float4 a = *(const float4*)src;
        float4 b = *(const float4*)(src + 4);
        bf16x8 o = {(bf16_t)a.x, (bf16_t)a.y, (bf16_t)a.z, (bf16_t)a.w,
                    (bf16_t)b.x, (bf16_t)b.y, (bf16_t)b.z, (bf16_t)b.w};
        *(bf16x8*)(WPf + (size_t)u * 8) = o;
    }
}

// ------------------------------------------------------------------
// Kernel M: rearrange mask (144x144x144 fp32) into MFMA C-fragment order.
// ------------------------------------------------------------------
__global__ __launch_bounds__(256) void kmask(const float* __restrict__ mask,
                                             float* __restrict__ maskR)
{
    int t = blockIdx.x * 256 + threadIdx.x;      // 0..746495
    int lane = t & 63;
    int g = t >> 6;
    int nt = g % 9;
    int g2 = g / 9;
    int wv = g2 % 9;
    int wm = g2 / 9;
    const float* src = mask + (size_t)wm * 20736
                     + (wv * 16 + (lane >> 4) * 4) * 144 + nt * 16 + (lane & 15);
    f32x4 v = { src[0], src[144], src[288], src[432] };
    *(f32x4*)(maskR + (size_t)t * 4) = v;
}

// ------------------------------------------------------------------
// Kernel X: convert a chunk of x (fp32) to bf16, 8 elems/thread.
// ------------------------------------------------------------------
__global__ __launch_bounds__(256) void kx(const float* __restrict__ x,
                                          bf16_t* __restrict__ xb, int n8)
{
    int i = blockIdx.x * 256 + threadIdx.x;
    if (i < n8) {
        float4 a = *(const float4*)(x + (size_t)i * 8);
        float4 b = *(const float4*)(x + (size_t)i * 8 + 4);
        bf16x8 o = {(bf16_t)a.x, (bf16_t)a.y, (bf16_t)a.z, (bf16_t)a.w,
                    (bf16_t)b.x, (bf16_t)b.y, (bf16_t)b.z, (bf16_t)b.w};
        *(bf16x8*)(xb + (size_t)i * 8) = o;
    }
}

// ------------------------------------------------------------------
// Kernel 1: QKV GEMM. A = xb bf16 via gload16 (double-buffered, source-side
// XOR swizzle so fragment ds_reads are conflict-free); B = WQf direct from
// global in fragment order (L2-resident). 128x128 tile, BK=64, 4 waves.
// Epilogue through LDS tile -> 16B stores to Q/K/VT.
// ------------------------------------------------------------------
__global__ __launch_bounds__(256) void k_qkv(const bf16_t* __restrict__ xb,
                                             const bf16_t* __restrict__ WQf,
                                             const float* __restrict__ bias,
                                             bf16_t* __restrict__ Qp,
                                             bf16_t* __restrict__ Kp,
                                             bf16_t* __restrict__ VTp)
{
    // bijective XCD-chunked swizzle (m204)
    int nwg = gridDim.x;
    int orig = blockIdx.x;
    int q8 = nwg >> 3, r8 = nwg & 7;
    int xcd = orig & 7, idx = orig >> 3;
    int wgid = (xcd < r8 ? xcd * (q8 + 1) : r8 * (q8 + 1) + (xcd - r8) * q8) + idx;
    int mb = wgid / 9, nb = wgid % 9;

    __shared__ union SMem {
        bf16_t A[2][128 * 64];       // 32 KB double-buffered A staging
        bf16_t tile[128 * 136];      // 34,816 B epilogue
    } sm;

    int tid = threadIdx.x;
    int lane = tid & 63, wid = tid >> 6;
    int wr = (wid >> 1) * 64, wc = (wid & 1) * 64;
    int l15 = lane & 15, l4 = lane >> 4;
    int lr8 = lane >> 3, lc8 = lane & 7;
    int lc8s = lc8 ^ lr8;                      // source-swizzled 16B slot (T2/G21)

    f32x4 acc[4][4] = {};

    // per-lane global source: row = mb*128 + wid*32 + p*8 + lr8, col-slot lc8s
    const bf16_t* aG = xb + ((size_t)mb * 128 + wid * 32 + lr8) * 384 + lc8s * 8;

    // prologue: stage kk=0 into buf 0
    #pragma unroll
    for (int p = 0; p < 4; ++p)
        gload16(aG + (size_t)p * (8 * 384), &sm.A[0][(wid * 4 + p) * 512]);

    for (int kk = 0; kk < 6; ++kk) {
        int buf = kk & 1;
        __syncthreads();                        // drains stage(kk)
        if (kk < 5) {                           // issue-early: stage(kk+1)
            #pragma unroll
            for (int p = 0; p < 4; ++p)
                gload16(aG + (size_t)p * (8 * 384) + (kk + 1) * 64,
                        &sm.A[buf ^ 1][(wid * 4 + p) * 512]);
        }
        #pragma unroll
        for (int kh = 0; kh < 2; ++kh) {
            bf16x8 af[4], bfr[4];
            #pragma unroll
            for (int j = 0; j < 4; ++j)        // B-frag: coalesced 16B from L2
                bfr[j] = *(const bf16x8*)(WQf +
                    ((((size_t)(nb * 6 + kk) * 2 + kh) * 8 + (wid & 1) * 4 + j) * 64 + lane) * 8);
            #pragma unroll
            for (int i = 0; i < 4; ++i) {      // A-frag: swizzled ds_read_b128
                int row = wr + i * 16 + l15;
                int slot = (kh * 4 + l4) ^ (l15 & 7);
                af[i] = *(const bf16x8*)&sm.A[buf][row * 64 + slot * 8];
            }
            #pragma unroll
            for (int i = 0; i < 4; ++i)
                #pragma unroll
                for (int j = 0; j < 4; ++j)
                    acc[i][j] = __builtin_amdgcn_mfma_f32_16x16x32_bf16(af[i], bfr[j], acc[i][j], 0, 0, 0);
        }
    }
    __syncthreads();   // all reads done before tile reuse

    // ---- epilogue: acc (+scaled bias) -> LDS tile -> vectorized stores ----
    const int S = 136;
    const float SCALE = 0.17677669529663687f;
    float scl = (nb < 3) ? SCALE : 1.0f;       // W pre-scaled; scale bias to match
    float bv[4];
    #pragma unroll
    for (int j = 0; j < 4; ++j) bv[j] = bias[nb * 128 + wc + j * 16 + l15] * scl;

    #pragma unroll
    for (int i = 0; i < 4; ++i)
        #pragma unroll
        for (int j = 0; j < 4; ++j)
            #pragma unroll
            for (int r = 0; r < 4; ++r)
                sm.tile[(wr + i * 16 + l4 * 4 + r) * S + wc + j * 16 + l15] =
                    (bf16_t)(acc[i][j][r] + bv[j]);
    __syncthreads();

    if (nb < 6) {
        bf16_t* dst = (nb < 3) ? Qp : Kp;
        int db0 = (nb % 3) * 128;
        #pragma unroll
        for (int it = 0; it < 8; ++it) {
            int item = tid + it * 256;
            int row = item >> 4, ch = item & 15;
            bf16x8 v = *(const bf16x8*)&sm.tile[row * S + ch * 8];
            int gr = mb * 128 + row;
            int lw = gr / 144, n = gr - lw * 144;
            int dl = db0 + ch * 8;
            int h = dl >> 5, c32 = dl & 31;
            *(bf16x8*)(dst + (size_t)(lw * 12 + h) * 4608 + n * 32 + c32) = v;
        }
    } else {
        int db0 = (nb - 6) * 128;
        #pragma unroll
        for (int it = 0; it < 8; ++it) {
            int item = tid + it * 256;
            int dl = item & 127;
            int nc = item >> 7;
            int gr0 = mb * 128 + nc * 8;
            int lw = gr0 / 144, n0 = gr0 - lw * 144;
            int rr = db0 + dl;
            int h = rr >> 5, j32 = rr & 31;
            bf16x8 v;
            #pragma unroll
            for (int q = 0; q < 8; ++q)
                v[q] = sm.tile[(nc * 8 + q) * S + dl];
            *(bf16x8*)(VTp + (size_t)(lw * 12 + h) * 4608 + j32 * 144 + n0) = v;
        }
    }
}

// ------------------------------------------------------------------
// Kernel 2: attention per (window, head). 576 threads = 9 waves.
// Mask as MFMA C-in fragments (maskR); XCD-swizzled grid.
// ------------------------------------------------------------------
__global__ __launch_bounds__(576) void k_attn(const bf16_t* __restrict__ Qp,
                                              const bf16_t* __restrict__ Kp,
                                              const bf16_t* __restrict__ VTp,
                                              const float* __restrict__ maskR,
                                              bf16_t* __restrict__ ao,
                                              int w0)
{
    extern __shared__ char smem[];
    bf16_t* kb  = (bf16_t*)smem;          // [144][40]  11,520 B
    bf16_t* vtb = kb + 144 * 40;          // [32][168]  10,752 B
    bf16_t* pb  = vtb + 32 * 168;         // [144][168] 48,384 B

    int nwg = gridDim.x;
    int orig = blockIdx.x;
    int q8 = nwg >> 3, r8 = nwg & 7;
    int xcd = orig & 7, idx = orig >> 3;
    int wgid = (xcd < r8 ? xcd * (q8 + 1) : r8 * (q8 + 1) + (xcd - r8) * q8) + idx;

    int bw = wgid / 12, h = wgid % 12;
    int W = w0 + bw;
    int wm = W % MASKW;
    size_t base = (size_t)(bw * 12 + h) * 4608;
    int tid = threadIdx.x;

    {
        int row = tid >> 2, c8 = (tid & 3) * 8;
        *(uint4*)&kb[row * 40 + c8] = *(const uint4*)(Kp + base + row * 32 + c8);
        int j = tid / 18, seg = tid % 18;
        *(uint4*)&vtb[j * 168 + seg * 8] = *(const uint4*)(VTp + base + j * 144 + seg * 8);
        if (tid < 64) {
            int jj = tid >> 1, cc = 144 + (tid & 1) * 8;
            uint4 z = {0, 0, 0, 0};
            *(uint4*)&vtb[jj * 168 + cc] = z;
        }
    }
    __syncthreads();

    int lane = tid & 63, wv = tid >> 6;
    int l15 = lane & 15, l4 = lane >> 4;
    int row16 = wv * 16;

    bf16x8 aq = *(const bf16x8*)(Qp + base + (row16 + l15) * 32 + l4 * 8);

    const float* mR = maskR + ((size_t)(wm * 9 + wv) * 9) * 256 + lane * 4;
    f32x4 s[9];
    #pragma unroll
    for (int nt = 0; nt < 9; ++nt) {
        bf16x8 bk = *(const bf16x8*)&kb[(nt * 16 + l15) * 40 + l4 * 8];
        f32x4 mv = *(const f32x4*)(mR + nt * 256);
        s[nt] = __builtin_amdgcn_mfma_f32_16x16x32_bf16(aq, bk, mv, 0, 0, 0);
    }

    float mx[4], sm[4];
    #pragma unroll
    for (int r = 0; r < 4; ++r) {
        float m = s[0][r];
        #pragma unroll
        for (int nt = 1; nt < 9; ++nt) m = fmaxf(m, s[nt][r]);
        #pragma unroll
        for (int off = 1; off < 16; off <<= 1) m = fmaxf(m, __shfl_xor(m, off, 64));
        mx[r] = m;
    }
    #pragma unroll
    for (int r = 0; r < 4; ++r) {
        float sum = 0.f;
        #pragma unroll
        for (int nt = 0; nt < 9; ++nt) {
            float e = __expf(s[nt][r] - mx[r]);
            s[nt][r] = e;
            sum += e;
        }
        #pragma unroll
        for (int off = 1; off < 16; off <<= 1) sum += __shfl_xor(sum, off, 64);
        sm[r] = sum;
    }

    #pragma unroll
    for (int nt = 0; nt < 9; ++nt)
        #pragma unroll
        for (int r = 0; r < 4; ++r)
            pb[(row16 + l4 * 4 + r) * 168 + nt * 16 + l15] = (bf16_t)s[nt][r];
    {
        int rr = lane >> 2, cc = 144 + (lane & 3) * 4;
        uint2 z = {0, 0};
        *(uint2*)&pb[(row16 + rr) * 168 + cc] = z;
    }
    f32x4 o0 = {0.f, 0.f, 0.f, 0.f}, o1 = {0.f, 0.f, 0.f, 0.f};
    #pragma unroll
    for (int ks = 0; ks < 5; ++ks) {
        bf16x8 ap  = *(const bf16x8*)&pb[(row16 + l15) * 168 + ks * 32 + l4 * 8];
        bf16x8 bv0 = *(const bf16x8*)&vtb[(l15) * 168 + ks * 32 + l4 * 8];
        bf16x8 bv1 = *(const bf16x8*)&vtb[(16 + l15) * 168 + ks * 32 + l4 * 8];
        o0 = __builtin_amdgcn_mfma_f32_16x16x32_bf16(ap, bv0, o0, 0, 0, 0);
        o1 = __builtin_amdgcn_mfma_f32_16x16x32_bf16(ap, bv1, o1, 0, 0, 0);
    }
    float inv[4];
    #pragma unroll
    for (int r = 0; r < 4; ++r) inv[r] = 1.0f / sm[r];
    bf16_t* ob = pb + row16 * 168;
    #pragma unroll
    for (int r = 0; r < 4; ++r) {
        ob[(l4 * 4 + r) * 32 + l15]      = (bf16_t)(o0[r] * inv[r]);
        ob[(l4 * 4 + r) * 32 + 16 + l15] = (bf16_t)(o1[r] * inv[r]);
    }
    bf16x8 v = *(const bf16x8*)&ob[(lane >> 2) * 32 + (lane & 3) * 8];
    *(bf16x8*)(ao + ((size_t)bw * 144 + row16 + (lane >> 2)) * 384 + h * 32 + (lane & 3) * 8) = v;
}

// ------------------------------------------------------------------
// Kernel 3: proj GEMM. Same structure as k_qkv: A = attn_out bf16 (gload16
// dbuf + swizzle), B = WPf direct fragment loads. fp32 out via 2-pass tile.
// ------------------------------------------------------------------
__global__ __launch_bounds__(256) void k_proj(const bf16_t* __restrict__ ao,
                                              const bf16_t* __restrict__ WPf,
                                              const float* __restrict__ bias,
                                              float* __restrict__ out,
                                              int rowoff)
{
    int nwg = gridDim.x;
    int orig = blockIdx.x;
    int q8 = nwg >> 3, r8 = nwg & 7;
    int xcd = orig & 7, idx = orig >> 3;
    int wgid = (xcd < r8 ? xcd * (q8 + 1) : r8 * (q8 + 1) + (xcd - r8) * q8) + idx;
    int mb = wgid / 3, nb = wgid % 3;

    __shared__ union SMem {
        bf16_t A[2][128 * 64];       // 32 KB
        float tile[128 * 68];        // 34,816 B
    } sm;

    int tid = threadIdx.x;
    int lane = tid & 63, wid = tid >> 6;
    int wr = (wid >> 1) * 64, wc = (wid & 1) * 64;
    int l15 = lane & 15, l4 = lane >> 4;
    int lr8 = lane >> 3, lc8 = lane & 7;
    int lc8s = lc8 ^ lr8;

    f32x4 acc[4][4] = {};

    const bf16_t* aG = ao + ((size_t)mb * 128 + wid * 32 + lr8) * 384 + lc8s * 8;

    #pragma unroll
    for (int p = 0; p < 4; ++p)
        gload16(aG + (size_t)p * (8 * 384), &sm.A[0][(wid * 4 + p) * 512]);

    for (int kk = 0; kk < 6; ++kk) {
        int buf = kk & 1;
        __syncthreads();
        if (kk < 5) {
            #pragma unroll
            for (int p = 0; p < 4; ++p)
                gload16(aG + (size_t)p * (8 * 384) + (kk + 1) * 64,
                        &sm.A[buf ^ 1][(wid * 4 + p) * 512]);
        }
        #pragma unroll
        for (int kh = 0; kh < 2; ++kh) {
            bf16x8 af[4], bfr[4];
            #pragma unroll
            for (int j = 0; j < 4; ++j)
                bfr[j] = *(const bf16x8*)(WPf +
                    ((((size_t)(nb * 6 + kk) * 2 + kh) * 8 + (wid & 1) * 4 + j) * 64 + lane) * 8);
            #pragma unroll
            for (int i = 0; i < 4; ++i) {
                int row = wr + i * 16 + l15;
                int slot = (kh * 4 + l4) ^ (l15 & 7);
                af[i] = *(const bf16x8*)&sm.A[buf][row * 64 + slot * 8];
            }
            #pragma unroll
            for (int i = 0; i < 4; ++i)
                #pragma unroll
                for (int j = 0; j < 4; ++j)
                    acc[i][j] = __builtin_amdgcn_mfma_f32_16x16x32_bf16(af[i], bfr[j], acc[i][j], 0, 0, 0);
        }
    }
    __syncthreads();

    float bv[4];
    #pragma unroll
    for (int j = 0; j < 4; ++j) bv[j] = bias[nb * 128 + wc + j * 16 + l15];

    #pragma unroll
    for (int half = 0; half < 2; ++half) {
        if (half) __syncthreads();
        if ((wid & 1) == half) {
            #pragma unroll
            for (int i = 0; i < 4; ++i)
                #pragma unroll
                for (int j = 0; j < 4; ++j)
                    #pragma unroll
                    for (int r = 0; r < 4; ++r)
                        sm.tile[(wr + i * 16 + l4 * 4 + r) * 68 + j * 16 + l15] =
                            acc[i][j][r] + bv[j];
        }
        __syncthreads();
        #pragma unroll
        for (int it = 0; it < 8; ++it) {
            int item = tid + it * 256;
            int row = item >> 4, ch = item & 15;
            float4 v = *(const float4*)&sm.tile[row * 68 + ch * 4];
            *(float4*)(out + (size_t)(rowoff + mb * 128 + row) * 384
                           + nb * 128 + half * 64 + ch * 4) = v;
        }
    }
}

// ------------------------------------------------------------------
extern "C" void kernel_launch(void* const* d_in, const int* in_sizes, int n_in,
                              void* d_out, int out_size, void* d_ws, size_t ws_size,
                              hipStream_t stream)
{
    const float* x     = (const float*)d_in[0];
    const float* mask  = (const float*)d_in[1];
    const float* qkvw  = (const float*)d_in[2];
    const float* qkvb  = (const float*)d_in[3];
    const float* projw = (const float*)d_in[4];
    const float* projb = (const float*)d_in[5];
    float* out = (float*)d_out;

    char* ws = (char*)d_ws;
    bf16_t* WQf  = (bf16_t*)ws;                     // packed qkv_w: 884,736 B
    bf16_t* WPf  = (bf16_t*)(ws + 884736);          // packed proj_w: 294,912 B
    float* maskR = (float*)(ws + 1179648);          // rearranged mask: 11,943,936 B
    char* chunkbase = ws + 13123584;

    // per-window bytes: xb + Q + K + VT + attn_out (all bf16) = 5 * 110,592
    size_t avail = ws_size > 13123584 ? ws_size - 13123584 : 0;
    long cw = (long)(avail / 552960);
    cw = (cw / 16) * 16;
    if (cw > NWIN) cw = NWIN;
    if (cw < 16) cw = 16;

    size_t qbytes = (size_t)cw * 110592;
    bf16_t* Xb  = (bf16_t*)chunkbase;
    bf16_t* Qp  = (bf16_t*)(chunkbase + qbytes);
    bf16_t* Kp  = (bf16_t*)(chunkbase + 2 * qbytes);
    bf16_t* VTp = (bf16_t*)(chunkbase + 3 * qbytes);
    bf16_t* AO  = (bf16_t*)(chunkbase + 4 * qbytes);

    kpack<<<288, 256, 0, stream>>>(qkvw, projw, WQf, WPf);
    kmask<<<2916, 256, 0, stream>>>(mask, maskR);

    for (int w0 = 0; w0 < NWIN; w0 += (int)cw) {
        int c = (int)((NWIN - w0) < cw ? (NWIN - w0) : cw);
        int n8 = c * 6912;
        kx<<<(n8 + 255) / 256, 256, 0, stream>>>(x + (size_t)w0 * 144 * 384, Xb, n8);
        int mblocks = (c * 144) / 128;
        k_qkv<<<mblocks * 9, 256, 0, stream>>>(Xb, WQf, qkvb, Qp, Kp, VTp);
        k_attn<<<c * 12, 576, 70656, stream>>>(Qp, Kp, VTp, maskR, AO, w0);
        k_proj<<<mblocks * 3, 256, 0, stream>>>(AO, WPf, projb, out, w0 * 144);
    }
}